// Round 13
// baseline (80.650 us; speedup 1.0000x reference)
//
#include <hip/hip_runtime.h>

// Le-ADMM reduction: state resets each iteration => output is one linear
// circular filter: out = crop_shift( IFFT2( K . FFT2(pad(x)) ) ),
// K = mu1[4]/((1+1e-6)*FH*FW) * conj(Hp) / (1e-6|Hp|^2 + 1e-5*PsiTPsi + 4e-5).
// Pairs packed z = x_a + i*x_b (K Hermitian => both results real).
//
// R12: HIGH-RADIX ROWS. R11's packed fp32 confirmed VALU-issue bound
// (83.4->73.5); rows (~38us) now dominate. Row schedule 8*8*6*5 (4 passes,
// 3 LDS round-trips, 2 rows/block) -> 12*16*10 (3 passes, 2 round-trips)
// at 4 rows/block so items/pass = 320/240/384 (>=240, R6 starvation rule).
// s1 radix-12 zero-pad-pruned (a[3..8] nonzero); mid16 in-place (1 item/
// thread); fin10 twiddle-free fused with Z-store / crop-split. Barriers
// 5->3, sincos -65%. LDS 65.3KB -> 2 blocks/CU (issue-bound kernels are
// occupancy-insensitive per R7/R9/R10). Keeps: R11 packed v2f math, R10
// K4 (B=4 radix-{10,12,[9K9],12,10} in-place), R3 XCD swizzle.

#define PI2 6.2831853071795864f

typedef float v2f __attribute__((ext_vector_type(2)));

__device__ __forceinline__ v2f vmk(float x, float y){ v2f r; r.x = x; r.y = y; return r; }
__device__ __forceinline__ v2f cmul(v2f a, v2f b){
    return vmk(a.x, a.x)*b + vmk(-a.y, a.y)*vmk(b.y, b.x);
}
__device__ __forceinline__ float4 pk(v2f a, v2f b){ return make_float4(a.x,a.y,b.x,b.y); }

// b64 pad (h single-row path): +1 v2f per 16.
__device__ __forceinline__ int IDX(int a){ return a + (a >> 4); }
#define IDXSZ(n) ((n) + ((n) >> 4))
// K2 v2f pad: +2 per 32 (float4-aligned).
__device__ __forceinline__ int IDXP(int a){ return a + ((a >> 5) << 1); }
#define IDXPSZ(n) ((n) + (((n) >> 5) << 1) + 4)
// float4-slot pad: +1 slot per 16.
__device__ __forceinline__ int IDX4(int a){ return a + (a >> 4); }
#define IDX4SZ(n) ((n) + ((n) >> 4) + 2)

// K2 pair LDS (v2f buffer, float4 access).
__device__ __forceinline__ void ldp(const v2f* __restrict__ b, int pos,
                                    v2f& v0, v2f& v1){
    const float4 t = *(const float4*)&b[IDXP(2*pos)];
    v0 = vmk(t.x,t.y); v1 = vmk(t.z,t.w);
}
__device__ __forceinline__ void stp(v2f* __restrict__ b, int pos,
                                    v2f v0, v2f v1){
    *(float4*)&b[IDXP(2*pos)] = pk(v0, v1);
}
// Grouped float4 LDS: slot = 2*pos + g (pair-group g).
__device__ __forceinline__ void ld4g(const float4* __restrict__ b, int pos, int g,
                                     v2f& v0, v2f& v1){
    const float4 t = b[IDX4(2*pos+g)];
    v0 = vmk(t.x,t.y); v1 = vmk(t.z,t.w);
}
__device__ __forceinline__ void st4g(float4* __restrict__ b, int pos, int g,
                                     v2f v0, v2f v1){
    b[IDX4(2*pos+g)] = pk(v0, v1);
}

template<int DIR>
__device__ __forceinline__ void dft3(v2f x0, v2f x1, v2f x2,
                                     v2f& y0, v2f& y1, v2f& y2)
{
    constexpr float s3 = (float)DIR * 0.8660254037844386f;
    v2f t = x1 + x2, u = x1 - x2;
    v2f m = x0 - 0.5f*t;
    v2f iu = vmk(-s3*u.y, s3*u.x);
    y0 = x0 + t; y1 = m + iu; y2 = m - iu;
}

template<int DIR>
__device__ __forceinline__ void dft4(v2f a0, v2f a1, v2f a2, v2f a3,
                                     v2f& b0, v2f& b1, v2f& b2, v2f& b3)
{
    v2f t0 = a0+a2, t1 = a0-a2, t2 = a1+a3, t3 = a1-a3;
    v2f j3 = vmk(-(float)DIR*t3.y, (float)DIR*t3.x);
    b0 = t0+t2; b2 = t0-t2; b1 = t1+j3; b3 = t1-j3;
}

template<int DIR>
__device__ __forceinline__ void dft6(const v2f a[6], v2f b[6])
{
    v2f e0,e1,e2,o0,o1,o2;
    dft3<DIR>(a[0],a[2],a[4], e0,e1,e2);
    dft3<DIR>(a[1],a[3],a[5], o0,o1,o2);
    constexpr float s3 = (float)DIR * 0.8660254037844386f;
    const v2f w1 = vmk( 0.5f, s3);
    const v2f w2 = vmk(-0.5f, s3);
    v2f t1 = cmul(w1,o1), t2 = cmul(w2,o2);
    b[0]=e0+o0; b[3]=e0-o0;
    b[1]=e1+t1; b[4]=e1-t1;
    b[2]=e2+t2; b[5]=e2-t2;
}

template<int DIR>
__device__ __forceinline__ void dft8(const v2f a[8], v2f b[8])
{
    v2f e0,e1,e2,e3,o0,o1,o2,o3;
    dft4<DIR>(a[0],a[2],a[4],a[6], e0,e1,e2,e3);
    dft4<DIR>(a[1],a[3],a[5],a[7], o0,o1,o2,o3);
    constexpr float c = 0.70710678118654752f;
    const v2f w1 = vmk( c, (float)DIR*c);
    const v2f w3 = vmk(-c, (float)DIR*c);
    v2f t1 = cmul(w1,o1);
    v2f t2 = vmk(-(float)DIR*o2.y, (float)DIR*o2.x);
    v2f t3 = cmul(w3,o3);
    b[0]=e0+o0; b[4]=e0-o0;
    b[1]=e1+t1; b[5]=e1-t1;
    b[2]=e2+t2; b[6]=e2-t2;
    b[3]=e3+t3; b[7]=e3-t3;
}

template<int DIR>
__device__ __forceinline__ void dft5(const v2f a[5], v2f b[5])
{
    constexpr float C1 = 0.30901699437494742f, S1c = 0.9510565162951535f;
    constexpr float C2 = -0.8090169943749475f, S2c = 0.5877852522924731f;
    v2f t1 = a[1]+a[4], t2 = a[2]+a[3], d1 = a[1]-a[4], d2 = a[2]-a[3];
    v2f m1 = a[0] + C1*t1 + C2*t2;
    v2f m2 = a[0] + C2*t1 + C1*t2;
    v2f e1 = S1c*d1 + S2c*d2;
    v2f e2 = S2c*d1 - S1c*d2;
    v2f ie1 = vmk(-(float)DIR*e1.y, (float)DIR*e1.x);
    v2f ie2 = vmk(-(float)DIR*e2.y, (float)DIR*e2.x);
    b[0] = a[0] + t1 + t2;
    b[1] = m1+ie1; b[4] = m1-ie1;
    b[2] = m2+ie2; b[3] = m2-ie2;
}

template<int DIR>
__device__ __forceinline__ void dft9(const v2f a[9], v2f b[9])
{
    v2f C0[3], C1[3], C2[3];
    dft3<DIR>(a[0],a[3],a[6], C0[0],C0[1],C0[2]);
    dft3<DIR>(a[1],a[4],a[7], C1[0],C1[1],C1[2]);
    dft3<DIR>(a[2],a[5],a[8], C2[0],C2[1],C2[2]);
    const v2f w91 = vmk(0.7660444431189780f, (float)DIR*0.6427876096865393f);
    const v2f w92 = vmk(0.1736481776669304f, (float)DIR*0.9848077530122081f);
    const v2f w94 = vmk(-0.9396926207859084f, (float)DIR*0.3420201433256687f);
    C1[1]=cmul(C1[1],w91); C1[2]=cmul(C1[2],w92);
    C2[1]=cmul(C2[1],w92); C2[2]=cmul(C2[2],w94);
    dft3<DIR>(C0[0],C1[0],C2[0], b[0],b[3],b[6]);
    dft3<DIR>(C0[1],C1[1],C2[1], b[1],b[4],b[7]);
    dft3<DIR>(C0[2],C1[2],C2[2], b[2],b[5],b[8]);
}

template<int DIR>
__device__ __forceinline__ void dft10(const v2f a[10], v2f b[10])
{
    v2f ae[5] = {a[0],a[2],a[4],a[6],a[8]};
    v2f ao[5] = {a[1],a[3],a[5],a[7],a[9]};
    v2f E[5], O[5];
    dft5<DIR>(ae, E); dft5<DIR>(ao, O);
    const v2f w1 = vmk( 0.8090169943749475f, (float)DIR*0.5877852522924731f);
    const v2f w2 = vmk( 0.3090169943749474f, (float)DIR*0.9510565162951535f);
    const v2f w3 = vmk(-0.3090169943749474f, (float)DIR*0.9510565162951535f);
    const v2f w4 = vmk(-0.8090169943749475f, (float)DIR*0.5877852522924731f);
    v2f t1 = cmul(O[1],w1), t2 = cmul(O[2],w2), t3 = cmul(O[3],w3), t4 = cmul(O[4],w4);
    b[0]=E[0]+O[0]; b[5]=E[0]-O[0];
    b[1]=E[1]+t1;   b[6]=E[1]-t1;
    b[2]=E[2]+t2;   b[7]=E[2]-t2;
    b[3]=E[3]+t3;   b[8]=E[3]-t3;
    b[4]=E[4]+t4;   b[9]=E[4]-t4;
}

template<int DIR>
__device__ __forceinline__ void dft12(const v2f a[12], v2f b[12])
{
    v2f C0[4], C1[4], C2[4];
    dft4<DIR>(a[0],a[3],a[6],a[9],  C0[0],C0[1],C0[2],C0[3]);
    dft4<DIR>(a[1],a[4],a[7],a[10], C1[0],C1[1],C1[2],C1[3]);
    dft4<DIR>(a[2],a[5],a[8],a[11], C2[0],C2[1],C2[2],C2[3]);
    const v2f w121 = vmk(0.8660254037844386f, (float)DIR*0.5f);
    const v2f w122 = vmk(0.5f, (float)DIR*0.8660254037844386f);
    const v2f w124 = vmk(-0.5f, (float)DIR*0.8660254037844386f);
    C1[1]=cmul(C1[1],w121); C1[2]=cmul(C1[2],w122);
    C1[3]=vmk(-(float)DIR*C1[3].y, (float)DIR*C1[3].x);
    C2[1]=cmul(C2[1],w122); C2[2]=cmul(C2[2],w124);
    C2[3]=-C2[3];
    dft3<DIR>(C0[0],C1[0],C2[0], b[0],b[4],b[8]);
    dft3<DIR>(C0[1],C1[1],C2[1], b[1],b[5],b[9]);
    dft3<DIR>(C0[2],C1[2],C2[2], b[2],b[6],b[10]);
    dft3<DIR>(C0[3],C1[3],C2[3], b[3],b[7],b[11]);
}

// dft16 = 4x4 CT: C_r = dft4(a_r,a_{r+4},a_{r+8},a_{r+12});
// d_r[m] = W16^{rm} C_r[m]; (X[m],X[m+4],X[m+8],X[m+12]) = dft4_r(d_*[m]).
template<int DIR>
__device__ __forceinline__ void dft16(const v2f a[16], v2f b[16])
{
    v2f C0[4], C1[4], C2[4], C3[4];
    dft4<DIR>(a[0],a[4],a[8], a[12], C0[0],C0[1],C0[2],C0[3]);
    dft4<DIR>(a[1],a[5],a[9], a[13], C1[0],C1[1],C1[2],C1[3]);
    dft4<DIR>(a[2],a[6],a[10],a[14], C2[0],C2[1],C2[2],C2[3]);
    dft4<DIR>(a[3],a[7],a[11],a[15], C3[0],C3[1],C3[2],C3[3]);
    const v2f w1 = vmk(0.9238795325112867f, (float)DIR*0.3826834323650898f);
    const v2f w2 = vmk(0.7071067811865476f, (float)DIR*0.7071067811865476f);
    const v2f w3 = vmk(0.3826834323650898f, (float)DIR*0.9238795325112867f);
    const v2f w6 = vmk(-0.7071067811865476f, (float)DIR*0.7071067811865476f);
    const v2f w9 = vmk(-0.9238795325112867f, -(float)DIR*0.3826834323650898f);
    C1[1]=cmul(C1[1],w1); C1[2]=cmul(C1[2],w2); C1[3]=cmul(C1[3],w3);
    C2[1]=cmul(C2[1],w2);
    C2[2]=vmk(-(float)DIR*C2[2].y, (float)DIR*C2[2].x);   // *W16^4 = i*DIR
    C2[3]=cmul(C2[3],w6);
    C3[1]=cmul(C3[1],w3); C3[2]=cmul(C3[2],w6); C3[3]=cmul(C3[3],w9);
    dft4<DIR>(C0[0],C1[0],C2[0],C3[0], b[0],b[4],b[8], b[12]);
    dft4<DIR>(C0[1],C1[1],C2[1],C3[1], b[1],b[5],b[9], b[13]);
    dft4<DIR>(C0[2],C1[2],C2[2],C3[2], b[2],b[6],b[10],b[14]);
    dft4<DIR>(C0[3],C1[3],C2[3],C3[3], b[3],b[7],b[11],b[15]);
}

// ============ h single-row path (b64, dbuf) ============

__device__ __forceinline__ void row_s1_fwd_h(const float* __restrict__ xa,
                                             v2f* __restrict__ bA, int tid)
{
    constexpr float STEP = -PI2 / 1920.0f;
    const v2f z = vmk(0.f,0.f);
    for (int p = tid; p < 240; p += 256) {
        v2f a[8], b[8];
        a[0]=z; a[1]=z; a[6]=z; a[7]=z;
        a[2] = vmk(xa[p],     0.f);
        a[3] = vmk(xa[p+240], 0.f);
        a[4] = vmk(xa[p+480], 0.f);
        a[5] = vmk(xa[p+720], 0.f);
        dft8<-1>(a,b);
        float sv, cv; __sincosf(STEP * (float)p, &sv, &cv);
        v2f w1 = vmk(cv, sv), w = w1;
        b[1] = cmul(b[1], w);
        #pragma unroll
        for (int u = 2; u < 8; ++u) { w = cmul(w, w1); b[u] = cmul(b[u], w); }
        #pragma unroll
        for (int u = 0; u < 8; ++u) bA[IDX(8*p + u)] = b[u];
    }
}

template<int DIR, int R, int NCUR, int S>
__device__ __forceinline__ void mid_stage(const v2f* __restrict__ src,
                                          v2f* __restrict__ dst, int tid)
{
    constexpr int M  = NCUR / R;
    constexpr int NB = M * S;
    constexpr float STEP = (float)DIR * PI2 / (float)NCUR;
    for (int i = tid; i < NB; i += 256) {
        const int p = i / S;
        v2f a[R], b[R];
        #pragma unroll
        for (int t = 0; t < R; ++t) a[t] = src[IDX(i + S*M*t)];
        if constexpr (R == 6) dft6<DIR>(a,b); else dft8<DIR>(a,b);
        float sv, cv; __sincosf(STEP * (float)p, &sv, &cv);
        v2f w1 = vmk(cv, sv), w = w1;
        b[1] = cmul(b[1], w);
        #pragma unroll
        for (int u = 2; u < R; ++u) { w = cmul(w, w1); b[u] = cmul(b[u], w); }
        const int ob = (i - p*S) + S*(R*p);
        #pragma unroll
        for (int u = 0; u < R; ++u) dst[IDX(ob + S*u)] = b[u];
    }
}

__device__ __forceinline__ void row_fin5_store_h(const v2f* __restrict__ src,
                                                 v2f* __restrict__ gdst, int tid)
{
    for (int q = tid; q < 384; q += 256) {
        v2f a[5], b[5];
        #pragma unroll
        for (int u = 0; u < 5; ++u) a[u] = src[IDX(q + 384*u)];
        dft5<-1>(a,b);
        #pragma unroll
        for (int u = 0; u < 5; ++u) gdst[q + 384*u] = b[u];
    }
}

// ============ row-quad path (4 rows/block, 1920 = 12*16*10, in-place) =====
// Group g = rows (2g, 2g+1); float4 slot 2*pos+g packs both rows' complex.

// s1 radix-12, S=1, fwd: padded cols 480..1439 nonzero -> samples p+160t,
// a[3..8] = x[p+160*(t-3)], rest 0. 320 items (loop), write-only.
__device__ __forceinline__ void rq_s1_fwd(const float* __restrict__ xa,
                                          const float* __restrict__ xb,
                                          float4* __restrict__ sb, int tid)
{
    constexpr float STEP = -PI2 / 1920.0f;
    const v2f z = vmk(0.f,0.f);
    for (int it = tid; it < 320; it += 256) {
        const int g = (it < 160) ? 0 : 1;
        const int p = it - 160*g;
        const float* xa0 = xa + (2*g)*960;
        const float* xb0 = xb + (2*g)*960;
        v2f a0[12], a1[12], b0[12], b1[12];
        a0[0]=a0[1]=a0[2]=a0[9]=a0[10]=a0[11]=z;
        a1[0]=a1[1]=a1[2]=a1[9]=a1[10]=a1[11]=z;
        #pragma unroll
        for (int s = 0; s < 6; ++s) {
            a0[3+s] = vmk(xa0[p+160*s],     xb0[p+160*s]);
            a1[3+s] = vmk(xa0[960+p+160*s], xb0[960+p+160*s]);
        }
        dft12<-1>(a0,b0); dft12<-1>(a1,b1);
        float sv, cv; __sincosf(STEP*(float)p, &sv, &cv);
        v2f w1 = vmk(cv,sv), w = w1;
        b0[1]=cmul(b0[1],w); b1[1]=cmul(b1[1],w);
        #pragma unroll
        for (int u = 2; u < 12; ++u){ w = cmul(w,w1); b0[u]=cmul(b0[u],w); b1[u]=cmul(b1[u],w); }
        #pragma unroll
        for (int u = 0; u < 12; ++u) st4g(sb, 12*p+u, g, b0[u], b1[u]);
    }
}

// s1 radix-12, inverse, full read from 4 spectrum rows.
__device__ __forceinline__ void rq_s1_inv(const v2f* __restrict__ Zbase,
                                          float4* __restrict__ sb, int tid)
{
    constexpr float STEP = PI2 / 1920.0f;
    for (int it = tid; it < 320; it += 256) {
        const int g = (it < 160) ? 0 : 1;
        const int p = it - 160*g;
        const v2f* Zr0 = Zbase + (2*g)*1920;
        const v2f* Zr1 = Zr0 + 1920;
        v2f a0[12], a1[12], b0[12], b1[12];
        #pragma unroll
        for (int t = 0; t < 12; ++t) { a0[t] = Zr0[p+160*t]; a1[t] = Zr1[p+160*t]; }
        dft12<1>(a0,b0); dft12<1>(a1,b1);
        float sv, cv; __sincosf(STEP*(float)p, &sv, &cv);
        v2f w1 = vmk(cv,sv), w = w1;
        b0[1]=cmul(b0[1],w); b1[1]=cmul(b1[1],w);
        #pragma unroll
        for (int u = 2; u < 12; ++u){ w = cmul(w,w1); b0[u]=cmul(b0[u],w); b1[u]=cmul(b1[u],w); }
        #pragma unroll
        for (int u = 0; u < 12; ++u) st4g(sb, 12*p+u, g, b0[u], b1[u]);
    }
}

// mid radix-16 in-place: NCUR=160, S=12, NB=120/group -> 240 items, 1/thread.
template<int DIR>
__device__ __forceinline__ void rq_mid16_ip(float4* __restrict__ sb, int tid)
{
    constexpr float STEP = (float)DIR * PI2 / 160.0f;
    const bool act = tid < 240;
    v2f b0[16], b1[16]; int ob = 0, g = 0;
    if (act) {
        g = (tid < 120) ? 0 : 1;
        const int ic = tid - 120*g;
        const int p = ic / 12;
        v2f a0[16], a1[16];
        #pragma unroll
        for (int t = 0; t < 16; ++t) ld4g(sb, ic + 120*t, g, a0[t], a1[t]);
        dft16<DIR>(a0,b0); dft16<DIR>(a1,b1);
        float sv, cv; __sincosf(STEP*(float)p, &sv, &cv);
        v2f w1 = vmk(cv,sv), w = w1;
        b0[1]=cmul(b0[1],w); b1[1]=cmul(b1[1],w);
        #pragma unroll
        for (int u = 2; u < 16; ++u){ w = cmul(w,w1); b0[u]=cmul(b0[u],w); b1[u]=cmul(b1[u],w); }
        ob = (ic - 12*p) + 192*p;
    }
    __syncthreads();
    if (act) {
        #pragma unroll
        for (int u = 0; u < 16; ++u) st4g(sb, ob + 12*u, g, b0[u], b1[u]);
    }
    __syncthreads();
}

// fin radix-10 fwd (p=0, twiddle-free): LDS -> 4 spectrum rows. 384 items.
__device__ __forceinline__ void rq_fin10_storeZ(const float4* __restrict__ sb,
                                                v2f* __restrict__ Zbase, int tid)
{
    for (int it = tid; it < 384; it += 256) {
        const int g = (it < 192) ? 0 : 1;
        const int q = it - 192*g;
        v2f* Zr0 = Zbase + (2*g)*1920;
        v2f* Zr1 = Zr0 + 1920;
        v2f a0[10],a1[10],b0[10],b1[10];
        #pragma unroll
        for (int u = 0; u < 10; ++u) ld4g(sb, q + 192*u, g, a0[u], a1[u]);
        dft10<-1>(a0,b0); dft10<-1>(a1,b1);
        #pragma unroll
        for (int u = 0; u < 10; ++u) { Zr0[q+192*u] = b0[u]; Zr1[q+192*u] = b1[u]; }
    }
}

// fin radix-10 inv + crop ((j+1440)%1920 remap) + split into 2 real images.
// n = q+192u kept: u=0 (j=q+480), u=1 (j=q+672), u=2 if q<96 (j=q+864),
// u=7 if q>=96 (j=q-96), u=8 (j=q+96), u=9 (j=q+288).
__device__ __forceinline__ void rq_fin10_crop(const float4* __restrict__ sb,
                                              float* __restrict__ oa, float* __restrict__ ob,
                                              int tid)
{
    for (int it = tid; it < 384; it += 256) {
        const int g = (it < 192) ? 0 : 1;
        const int q = it - 192*g;
        float* oa0 = oa + (2*g)*960; float* ob0 = ob + (2*g)*960;
        float* oa1 = oa0 + 960;      float* ob1 = ob0 + 960;
        v2f a0[10],a1[10],b0[10],b1[10];
        #pragma unroll
        for (int u = 0; u < 10; ++u) ld4g(sb, q + 192*u, g, a0[u], a1[u]);
        dft10<1>(a0,b0); dft10<1>(a1,b1);
        oa0[q+480] = b0[0].x; ob0[q+480] = b0[0].y;
        oa1[q+480] = b1[0].x; ob1[q+480] = b1[0].y;
        oa0[q+672] = b0[1].x; ob0[q+672] = b0[1].y;
        oa1[q+672] = b1[1].x; ob1[q+672] = b1[1].y;
        if (q < 96)  { oa0[q+864] = b0[2].x; ob0[q+864] = b0[2].y;
                       oa1[q+864] = b1[2].x; ob1[q+864] = b1[2].y; }
        if (q >= 96) { oa0[q-96]  = b0[7].x; ob0[q-96]  = b0[7].y;
                       oa1[q-96]  = b1[7].x; ob1[q-96]  = b1[7].y; }
        oa0[q+96]  = b0[8].x; ob0[q+96]  = b0[8].y;
        oa1[q+96]  = b1[8].x; ob1[q+96]  = b1[8].y;
        oa0[q+288] = b0[9].x; ob0[q+288] = b0[9].y;
        oa1[q+288] = b1[9].x; ob1[q+288] = b1[9].y;
    }
}

// ============ K2 column path (sincos, pair-per-thread, dbuf) ============

__device__ __forceinline__ void col_s1_fwd_pair(const v2f* __restrict__ g, int c0,
                                                v2f* __restrict__ bA, int tid)
{
    constexpr float STEP = -PI2 / 1080.0f;
    const v2f z = vmk(0.f,0.f);
    const float4* gc = (const float4*)(g + c0);
    for (int p = tid; p < 180; p += 256) {
        v2f a0[6], a1[6], b0[6], b1[6];
        a0[0]=a0[5]=a1[0]=a1[5]=z;
        if (p >= 90) { float4 t = gc[(p-90)*960]; a0[1]=vmk(t.x,t.y); a1[1]=vmk(t.z,t.w); }
        else         { a0[1]=a1[1]=z; }
        { float4 t = gc[(p+90)*960];  a0[2]=vmk(t.x,t.y); a1[2]=vmk(t.z,t.w); }
        { float4 t = gc[(p+270)*960]; a0[3]=vmk(t.x,t.y); a1[3]=vmk(t.z,t.w); }
        if (p < 90)  { float4 t = gc[(p+450)*960]; a0[4]=vmk(t.x,t.y); a1[4]=vmk(t.z,t.w); }
        else         { a0[4]=a1[4]=z; }
        dft6<-1>(a0,b0); dft6<-1>(a1,b1);
        float sv, cv; __sincosf(STEP*(float)p, &sv, &cv);
        v2f w1 = vmk(cv,sv), w = w1;
        b0[1]=cmul(b0[1],w); b1[1]=cmul(b1[1],w);
        #pragma unroll
        for (int u = 2; u < 6; ++u){ w = cmul(w,w1); b0[u]=cmul(b0[u],w); b1[u]=cmul(b1[u],w); }
        #pragma unroll
        for (int u = 0; u < 6; ++u) stp(bA, 6*p + u, b0[u], b1[u]);
    }
}

template<int DIR, int NCUR, int SC>
__device__ __forceinline__ void mid_pair(const v2f* __restrict__ src,
                                         v2f* __restrict__ dst, int tid)
{
    constexpr int NB = 180;
    constexpr float STEP = (float)DIR * PI2 / (float)NCUR;
    for (int ic = tid; ic < NB; ic += 256) {
        const int p = ic / SC;
        v2f a0[6], a1[6], b0[6], b1[6];
        #pragma unroll
        for (int t = 0; t < 6; ++t) ldp(src, ic + NB*t, a0[t], a1[t]);
        dft6<DIR>(a0,b0); dft6<DIR>(a1,b1);
        float sv, cv; __sincosf(STEP*(float)p, &sv, &cv);
        v2f w1 = vmk(cv,sv), w = w1;
        b0[1]=cmul(b0[1],w); b1[1]=cmul(b1[1],w);
        #pragma unroll
        for (int u = 2; u < 6; ++u){ w = cmul(w,w1); b0[u]=cmul(b0[u],w); b1[u]=cmul(b1[u],w); }
        const int ob = (ic - p*SC) + SC*6*p;
        #pragma unroll
        for (int u = 0; u < 6; ++u) stp(dst, ob + SC*u, b0[u], b1[u]);
    }
}

// ============ K4 B=4 high-radix in-place pieces ============

__device__ __forceinline__ void c4_s1_fwd10(const v2f* __restrict__ Zp, int c0,
                                            float4* __restrict__ sb, int tid)
{
    constexpr float STEP = -PI2 / 1080.0f;
    const v2f z = vmk(0.f,0.f);
    const float4* gc = (const float4*)(Zp + c0);
    const bool act = tid < 216;
    if (act) {
        const int g = tid & 1, p = tid >> 1;
        v2f a0[10], a1[10], b0[10], b1[10];
        a0[0]=a0[1]=a0[8]=a0[9]=z; a1[0]=a1[1]=a1[8]=a1[9]=z;
        if (p >= 54) { float4 t = gc[(p-54)*960+g]; a0[2]=vmk(t.x,t.y); a1[2]=vmk(t.z,t.w); }
        else         { a0[2]=a1[2]=z; }
        { float4 t = gc[(p+54)*960+g];  a0[3]=vmk(t.x,t.y); a1[3]=vmk(t.z,t.w); }
        { float4 t = gc[(p+162)*960+g]; a0[4]=vmk(t.x,t.y); a1[4]=vmk(t.z,t.w); }
        { float4 t = gc[(p+270)*960+g]; a0[5]=vmk(t.x,t.y); a1[5]=vmk(t.z,t.w); }
        { float4 t = gc[(p+378)*960+g]; a0[6]=vmk(t.x,t.y); a1[6]=vmk(t.z,t.w); }
        if (p < 54)  { float4 t = gc[(p+486)*960+g]; a0[7]=vmk(t.x,t.y); a1[7]=vmk(t.z,t.w); }
        else         { a0[7]=a1[7]=z; }
        dft10<-1>(a0,b0); dft10<-1>(a1,b1);
        float sv, cv; __sincosf(STEP*(float)p, &sv, &cv);
        v2f w1 = vmk(cv,sv), w = w1;
        b0[1]=cmul(b0[1],w); b1[1]=cmul(b1[1],w);
        #pragma unroll
        for (int u = 2; u < 10; ++u){ w = cmul(w,w1); b0[u]=cmul(b0[u],w); b1[u]=cmul(b1[u],w); }
        #pragma unroll
        for (int u = 0; u < 10; ++u) st4g(sb, 10*p+u, g, b0[u], b1[u]);
    }
    __syncthreads();
}

template<int DIR, int NCUR, int SC>
__device__ __forceinline__ void c4_mid12_ip(float4* __restrict__ sb, int tid)
{
    constexpr int NB = (NCUR/12)*SC;   // 90
    constexpr float STEP = (float)DIR * PI2 / (float)NCUR;
    const bool act = tid < 2*NB;
    v2f b0[12], b1[12]; int ob = 0, g = 0;
    if (act) {
        g = tid & 1;
        const int ic = tid >> 1;
        const int p = ic / SC;
        v2f a0[12], a1[12];
        #pragma unroll
        for (int t = 0; t < 12; ++t) ld4g(sb, ic + NB*t, g, a0[t], a1[t]);
        dft12<DIR>(a0,b0); dft12<DIR>(a1,b1);
        float sv, cv; __sincosf(STEP*(float)p, &sv, &cv);
        v2f w1 = vmk(cv,sv), w = w1;
        b0[1]=cmul(b0[1],w); b1[1]=cmul(b1[1],w);
        #pragma unroll
        for (int u = 2; u < 12; ++u){ w = cmul(w,w1); b0[u]=cmul(b0[u],w); b1[u]=cmul(b1[u],w); }
        ob = (ic - p*SC) + SC*12*p;
    }
    __syncthreads();
    if (act) {
        #pragma unroll
        for (int u = 0; u < 12; ++u) st4g(sb, ob + SC*u, g, b0[u], b1[u]);
    }
    __syncthreads();
}

__device__ __forceinline__ void c4_f9K9_ip(float4* __restrict__ sb,
                                           const float4* __restrict__ KI,
                                           int cg, int tid)
{
    constexpr float STEP = PI2 / 1080.0f;
    const bool act = tid < 240;
    v2f d0[9], d1[9]; int q = 0, g = 0;
    if (act) {
        g = tid & 1; q = tid >> 1;
        const float4* Kc = KI + (cg*2 + g)*1080;
        v2f a0[9], a1[9], s0[9], s1[9];
        #pragma unroll
        for (int u = 0; u < 9; ++u) ld4g(sb, q + 120*u, g, a0[u], a1[u]);
        dft9<-1>(a0,s0); dft9<-1>(a1,s1);
        #pragma unroll
        for (int u = 0; u < 9; ++u) {
            float4 kk = Kc[q + 120*u];
            s0[u] = cmul(s0[u], vmk(kk.x,kk.y));
            s1[u] = cmul(s1[u], vmk(kk.z,kk.w));
        }
        dft9<1>(s0,d0); dft9<1>(s1,d1);
        float sv, cv; __sincosf(STEP*(float)q, &sv, &cv);
        v2f w1 = vmk(cv,sv), w = w1;
        d0[1]=cmul(d0[1],w); d1[1]=cmul(d1[1],w);
        #pragma unroll
        for (int u = 2; u < 9; ++u){ w = cmul(w,w1); d0[u]=cmul(d0[u],w); d1[u]=cmul(d1[u],w); }
    }
    __syncthreads();
    if (act) {
        #pragma unroll
        for (int u = 0; u < 9; ++u) st4g(sb, 9*q + u, g, d0[u], d1[u]);
    }
    __syncthreads();
}

__device__ __forceinline__ void c4_fin10_crop(const float4* __restrict__ sb,
                                              v2f* __restrict__ Zp,
                                              int c0, int tid)
{
    const bool act = tid < 216;
    if (!act) return;
    const int g = tid & 1, q = tid >> 1;
    float4* gc = (float4*)(Zp + c0);
    v2f a0[10], a1[10], b0[10], b1[10];
    #pragma unroll
    for (int u = 0; u < 10; ++u) ld4g(sb, q + 108*u, g, a0[u], a1[u]);
    dft10<1>(a0,b0); dft10<1>(a1,b1);
    gc[(q+270)*960+g] = pk(b0[0], b1[0]);
    gc[(q+378)*960+g] = pk(b0[1], b1[1]);
    if (q < 54)  gc[(q+486)*960+g] = pk(b0[2], b1[2]);
    if (q >= 54) gc[(q-54)*960+g]  = pk(b0[7], b1[7]);
    gc[(q+54)*960+g]  = pk(b0[8], b1[8]);
    gc[(q+162)*960+g] = pk(b0[9], b1[9]);
}

// ============ kernels ============

// K13: blocks [0,540): x quads (4 rows of one plane); [540,1080): h rows.
__global__ __launch_bounds__(256,2) void k_row_fwd(const float* __restrict__ x,
                                                   const float* __restrict__ h,
                                                   v2f* __restrict__ Z,
                                                   v2f* __restrict__ Hrow)
{
    __shared__ float4 sb[IDX4SZ(3840)];
    const int tid = threadIdx.x;
    if (blockIdx.x < 540) {
        const int pp = blockIdx.x / 135;
        const int r0 = (blockIdx.x % 135) * 4;
        const float* xa = x + ((2*pp  )*540 + r0)*960;
        const float* xb = x + ((2*pp+1)*540 + r0)*960;
        rq_s1_fwd(xa, xb, sb, tid); __syncthreads();
        rq_mid16_ip<-1>(sb, tid);
        rq_fin10_storeZ(sb, Z + (pp*540 + r0)*1920, tid);
    } else {
        v2f* bA = (v2f*)sb;
        v2f* bB = bA + IDXSZ(1920);
        const int r = blockIdx.x - 540;
        row_s1_fwd_h(h + r*960, bA, tid); __syncthreads();
        mid_stage<-1,8,240, 8>(bA, bB, tid); __syncthreads();
        mid_stage<-1,6, 30,64>(bB, bA, tid); __syncthreads();
        row_fin5_store_h(bA, Hrow + r*1920, tid);
    }
}

// K2: column FFTs of Hrow (pair/thread, dbuf) + build pair-interleaved KI.
__global__ __launch_bounds__(256,4) void k_col_fft_h_buildK(const v2f* __restrict__ Hrow,
                                                            const float* __restrict__ mu1,
                                                            float4* __restrict__ KI)
{
    __shared__ v2f bA[IDXPSZ(2160)], bB[IDXPSZ(2160)];
    const int tid = threadIdx.x;
    const int xcd = blockIdx.x & 7, idx = blockIdx.x >> 3;
    const int cpair = xcd*120 + idx, c0 = cpair*2;
    col_s1_fwd_pair(Hrow, c0, bA, tid);  __syncthreads();
    mid_pair<-1,180, 6>(bA, bB, tid);    __syncthreads();
    mid_pair<-1, 30,36>(bB, bA, tid);    __syncthreads();
    const float sc = mu1[4] / ((1.0f + 1e-6f) * 2073600.0f);
    const float cos0 = __cosf(PI2 * (float)(c0  ) * (1.0f/1920.0f));
    const float cos1 = __cosf(PI2 * (float)(c0+1) * (1.0f/1920.0f));
    float4* Kc = KI + cpair*1080;
    for (int p = tid; p < 216; p += 256) {
        v2f a0[5],a1[5],b0[5],b1[5];
        #pragma unroll
        for (int u = 0; u < 5; ++u) ldp(bA, p + 216*u, a0[u], a1[u]);
        dft5<-1>(a0,b0); dft5<-1>(a1,b1);
        #pragma unroll
        for (int u = 0; u < 5; ++u) {
            const int k = p + 216*u;
            const float cosk = __cosf(PI2 * (float)k * (1.0f/1080.0f));
            float m0 = b0[u].x*b0[u].x + b0[u].y*b0[u].y;
            float m1 = b1[u].x*b1[u].x + b1[u].y*b1[u].y;
            float f0 = sc / (1e-6f*m0 + 1e-5f*(4.0f - 2.0f*cosk - 2.0f*cos0) + 4e-5f);
            float f1 = sc / (1e-6f*m1 + 1e-5f*(4.0f - 2.0f*cosk - 2.0f*cos1) + 4e-5f);
            Kc[k] = make_float4(f0*b0[u].x, -f0*b0[u].y, f1*b1[u].x, -f1*b1[u].y);
        }
    }
}

// K4: B=4 columns/block, radix {10,12,[9 K 9],12,10}, IN-PLACE (36.7KB LDS,
// 4 blocks/CU). Grid 1920; XCD swizzle.
__global__ __launch_bounds__(256,4) void k_col_fused(v2f* __restrict__ Z,
                                                     const float4* __restrict__ KI)
{
    __shared__ float4 sb[IDX4SZ(2160)];
    const int tid = threadIdx.x;
    const int xcd = blockIdx.x & 7, idx = blockIdx.x >> 3;   // idx in [0,240)
    const int pp  = idx / 60;
    const int cg  = xcd*60 + (idx - pp*60);                  // col-group [0,480)
    const int c0  = cg*4;
    v2f* Zp = Z + pp*540*1920;
    c4_s1_fwd10(Zp, c0, sb, tid);
    c4_mid12_ip<-1,108,10>(sb, tid);
    c4_f9K9_ip(sb, KI, cg, tid);
    c4_mid12_ip< 1,120, 9>(sb, tid);
    c4_fin10_crop(sb, Zp, c0, tid);
}

// K5: row inverse FFTs, 4 rows/block + crop + split into real outputs.
__global__ __launch_bounds__(256,2) void k_row_inv_out(const v2f* __restrict__ Z,
                                                       float* __restrict__ out)
{
    __shared__ float4 sb[IDX4SZ(3840)];
    const int tid = threadIdx.x;
    const int pp = blockIdx.x / 135;
    const int r0 = (blockIdx.x % 135) * 4;
    rq_s1_inv(Z + (pp*540 + r0)*1920, sb, tid); __syncthreads();
    rq_mid16_ip<1>(sb, tid);
    rq_fin10_crop(sb, out + ((2*pp)*540 + r0)*960, out + ((2*pp+1)*540 + r0)*960, tid);
}

extern "C" void kernel_launch(void* const* d_in, const int* in_sizes, int n_in,
                              void* d_out, int out_size, void* d_ws, size_t ws_size,
                              hipStream_t stream)
{
    (void)in_sizes; (void)n_in; (void)out_size; (void)ws_size;
    const float* x   = (const float*)d_in[0];
    const float* h   = (const float*)d_in[1];
    const float* mu1 = (const float*)d_in[2];
    float*       out = (float*)d_out;

    // ws layout: KI (960*1080 f4 = 16.6MB) | Z (4*540*1920 v2f = 33.2MB) |
    // Hrow (540*1920 v2f = 8.3MB).
    float4* KI   = (float4*)d_ws;
    v2f*    Z    = (v2f*)(KI + 960*1080);
    v2f*    Hrow = Z + 4*540*1920;

    k_row_fwd         <<<1080,   256, 0, stream>>>(x, h, Z, Hrow);
    k_col_fft_h_buildK<<<960,    256, 0, stream>>>(Hrow, mu1, KI);
    k_col_fused       <<<1920,   256, 0, stream>>>(Z, KI);
    k_row_inv_out     <<<540,    256, 0, stream>>>(Z, out);
}

// Round 14
// 73.721 us; speedup vs baseline: 1.0940x; 1.0940x over previous
//
#include <hip/hip_runtime.h>

// Le-ADMM reduction: state resets each iteration => output is one linear
// circular filter: out = crop_shift( IFFT2( K . FFT2(pad(x)) ) ),
// K = mu1[4]/((1+1e-6)*FH*FW) * conj(Hp) / (1e-6|Hp|^2 + 1e-5*PsiTPsi + 4e-5).
// Pairs packed z = x_a + i*x_b (K Hermitian => both results real).
//
// R13: REVERT to R11 (best measured: 73.5us). R12's radix-16 rows (4 rows/
// block) regressed 73.5->80.7: ~128 live VGPRs of butterfly state at
// 2 blocks/CU. Ledger rule: radix <= 12 with >= 2 packed groups is the
// register sweet-spot limit. Config: packed v2f math (R11, -12%), paired
// rows 8*8*6*5 in-place (R9), K4 B=4 radix-{10,12,[9K9],12,10} in-place
// (R10), XCD-chunked swizzle (R3), zero-pad/crop fusion throughout.

#define PI2 6.2831853071795864f

typedef float v2f __attribute__((ext_vector_type(2)));

__device__ __forceinline__ v2f vmk(float x, float y){ v2f r; r.x = x; r.y = y; return r; }
__device__ __forceinline__ v2f cmul(v2f a, v2f b){
    return vmk(a.x, a.x)*b + vmk(-a.y, a.y)*vmk(b.y, b.x);
}
__device__ __forceinline__ float4 pk(v2f a, v2f b){ return make_float4(a.x,a.y,b.x,b.y); }

// b64 pad (h single-row path): +1 v2f per 16.
__device__ __forceinline__ int IDX(int a){ return a + (a >> 4); }
#define IDXSZ(n) ((n) + ((n) >> 4))
// K2 v2f pad: +2 per 32 (float4-aligned).
__device__ __forceinline__ int IDXP(int a){ return a + ((a >> 5) << 1); }
#define IDXPSZ(n) ((n) + (((n) >> 5) << 1) + 4)
// float4-slot pad: +1 slot per 16.
__device__ __forceinline__ int IDX4(int a){ return a + (a >> 4); }
#define IDX4SZ(n) ((n) + ((n) >> 4) + 2)

// K2 pair LDS (v2f buffer, float4 access).
__device__ __forceinline__ void ldp(const v2f* __restrict__ b, int pos,
                                    v2f& v0, v2f& v1){
    const float4 t = *(const float4*)&b[IDXP(2*pos)];
    v0 = vmk(t.x,t.y); v1 = vmk(t.z,t.w);
}
__device__ __forceinline__ void stp(v2f* __restrict__ b, int pos,
                                    v2f v0, v2f v1){
    *(float4*)&b[IDXP(2*pos)] = pk(v0, v1);
}
// Row-pair LDS (float4 buffer).
__device__ __forceinline__ void ld4(const float4* __restrict__ b, int pos,
                                    v2f& v0, v2f& v1){
    const float4 t = b[IDX4(pos)];
    v0 = vmk(t.x,t.y); v1 = vmk(t.z,t.w);
}
__device__ __forceinline__ void st4(float4* __restrict__ b, int pos,
                                    v2f v0, v2f v1){
    b[IDX4(pos)] = pk(v0, v1);
}
// K4 B=4 LDS: slot = 2*pos + g (g = pair group 0/1).
__device__ __forceinline__ void ld4g(const float4* __restrict__ b, int pos, int g,
                                     v2f& v0, v2f& v1){
    const float4 t = b[IDX4(2*pos+g)];
    v0 = vmk(t.x,t.y); v1 = vmk(t.z,t.w);
}
__device__ __forceinline__ void st4g(float4* __restrict__ b, int pos, int g,
                                     v2f v0, v2f v1){
    b[IDX4(2*pos+g)] = pk(v0, v1);
}

template<int DIR>
__device__ __forceinline__ void dft3(v2f x0, v2f x1, v2f x2,
                                     v2f& y0, v2f& y1, v2f& y2)
{
    constexpr float s3 = (float)DIR * 0.8660254037844386f;
    v2f t = x1 + x2, u = x1 - x2;
    v2f m = x0 - 0.5f*t;
    v2f iu = vmk(-s3*u.y, s3*u.x);
    y0 = x0 + t; y1 = m + iu; y2 = m - iu;
}

template<int DIR>
__device__ __forceinline__ void dft4(v2f a0, v2f a1, v2f a2, v2f a3,
                                     v2f& b0, v2f& b1, v2f& b2, v2f& b3)
{
    v2f t0 = a0+a2, t1 = a0-a2, t2 = a1+a3, t3 = a1-a3;
    v2f j3 = vmk(-(float)DIR*t3.y, (float)DIR*t3.x);
    b0 = t0+t2; b2 = t0-t2; b1 = t1+j3; b3 = t1-j3;
}

template<int DIR>
__device__ __forceinline__ void dft6(const v2f a[6], v2f b[6])
{
    v2f e0,e1,e2,o0,o1,o2;
    dft3<DIR>(a[0],a[2],a[4], e0,e1,e2);
    dft3<DIR>(a[1],a[3],a[5], o0,o1,o2);
    constexpr float s3 = (float)DIR * 0.8660254037844386f;
    const v2f w1 = vmk( 0.5f, s3);
    const v2f w2 = vmk(-0.5f, s3);
    v2f t1 = cmul(w1,o1), t2 = cmul(w2,o2);
    b[0]=e0+o0; b[3]=e0-o0;
    b[1]=e1+t1; b[4]=e1-t1;
    b[2]=e2+t2; b[5]=e2-t2;
}

template<int DIR>
__device__ __forceinline__ void dft8(const v2f a[8], v2f b[8])
{
    v2f e0,e1,e2,e3,o0,o1,o2,o3;
    dft4<DIR>(a[0],a[2],a[4],a[6], e0,e1,e2,e3);
    dft4<DIR>(a[1],a[3],a[5],a[7], o0,o1,o2,o3);
    constexpr float c = 0.70710678118654752f;
    const v2f w1 = vmk( c, (float)DIR*c);
    const v2f w3 = vmk(-c, (float)DIR*c);
    v2f t1 = cmul(w1,o1);
    v2f t2 = vmk(-(float)DIR*o2.y, (float)DIR*o2.x);
    v2f t3 = cmul(w3,o3);
    b[0]=e0+o0; b[4]=e0-o0;
    b[1]=e1+t1; b[5]=e1-t1;
    b[2]=e2+t2; b[6]=e2-t2;
    b[3]=e3+t3; b[7]=e3-t3;
}

template<int DIR>
__device__ __forceinline__ void dft5(const v2f a[5], v2f b[5])
{
    constexpr float C1 = 0.30901699437494742f, S1c = 0.9510565162951535f;
    constexpr float C2 = -0.8090169943749475f, S2c = 0.5877852522924731f;
    v2f t1 = a[1]+a[4], t2 = a[2]+a[3], d1 = a[1]-a[4], d2 = a[2]-a[3];
    v2f m1 = a[0] + C1*t1 + C2*t2;
    v2f m2 = a[0] + C2*t1 + C1*t2;
    v2f e1 = S1c*d1 + S2c*d2;
    v2f e2 = S2c*d1 - S1c*d2;
    v2f ie1 = vmk(-(float)DIR*e1.y, (float)DIR*e1.x);
    v2f ie2 = vmk(-(float)DIR*e2.y, (float)DIR*e2.x);
    b[0] = a[0] + t1 + t2;
    b[1] = m1+ie1; b[4] = m1-ie1;
    b[2] = m2+ie2; b[3] = m2-ie2;
}

// dft9 / dft10 / dft12 (structure verified R6/R10).
template<int DIR>
__device__ __forceinline__ void dft9(const v2f a[9], v2f b[9])
{
    v2f C0[3], C1[3], C2[3];
    dft3<DIR>(a[0],a[3],a[6], C0[0],C0[1],C0[2]);
    dft3<DIR>(a[1],a[4],a[7], C1[0],C1[1],C1[2]);
    dft3<DIR>(a[2],a[5],a[8], C2[0],C2[1],C2[2]);
    const v2f w91 = vmk(0.7660444431189780f, (float)DIR*0.6427876096865393f);
    const v2f w92 = vmk(0.1736481776669304f, (float)DIR*0.9848077530122081f);
    const v2f w94 = vmk(-0.9396926207859084f, (float)DIR*0.3420201433256687f);
    C1[1]=cmul(C1[1],w91); C1[2]=cmul(C1[2],w92);
    C2[1]=cmul(C2[1],w92); C2[2]=cmul(C2[2],w94);
    dft3<DIR>(C0[0],C1[0],C2[0], b[0],b[3],b[6]);
    dft3<DIR>(C0[1],C1[1],C2[1], b[1],b[4],b[7]);
    dft3<DIR>(C0[2],C1[2],C2[2], b[2],b[5],b[8]);
}

template<int DIR>
__device__ __forceinline__ void dft10(const v2f a[10], v2f b[10])
{
    v2f ae[5] = {a[0],a[2],a[4],a[6],a[8]};
    v2f ao[5] = {a[1],a[3],a[5],a[7],a[9]};
    v2f E[5], O[5];
    dft5<DIR>(ae, E); dft5<DIR>(ao, O);
    const v2f w1 = vmk( 0.8090169943749475f, (float)DIR*0.5877852522924731f);
    const v2f w2 = vmk( 0.3090169943749474f, (float)DIR*0.9510565162951535f);
    const v2f w3 = vmk(-0.3090169943749474f, (float)DIR*0.9510565162951535f);
    const v2f w4 = vmk(-0.8090169943749475f, (float)DIR*0.5877852522924731f);
    v2f t1 = cmul(O[1],w1), t2 = cmul(O[2],w2), t3 = cmul(O[3],w3), t4 = cmul(O[4],w4);
    b[0]=E[0]+O[0]; b[5]=E[0]-O[0];
    b[1]=E[1]+t1;   b[6]=E[1]-t1;
    b[2]=E[2]+t2;   b[7]=E[2]-t2;
    b[3]=E[3]+t3;   b[8]=E[3]-t3;
    b[4]=E[4]+t4;   b[9]=E[4]-t4;
}

template<int DIR>
__device__ __forceinline__ void dft12(const v2f a[12], v2f b[12])
{
    v2f C0[4], C1[4], C2[4];
    dft4<DIR>(a[0],a[3],a[6],a[9],  C0[0],C0[1],C0[2],C0[3]);
    dft4<DIR>(a[1],a[4],a[7],a[10], C1[0],C1[1],C1[2],C1[3]);
    dft4<DIR>(a[2],a[5],a[8],a[11], C2[0],C2[1],C2[2],C2[3]);
    const v2f w121 = vmk(0.8660254037844386f, (float)DIR*0.5f);
    const v2f w122 = vmk(0.5f, (float)DIR*0.8660254037844386f);
    const v2f w124 = vmk(-0.5f, (float)DIR*0.8660254037844386f);
    C1[1]=cmul(C1[1],w121); C1[2]=cmul(C1[2],w122);
    C1[3]=vmk(-(float)DIR*C1[3].y, (float)DIR*C1[3].x);
    C2[1]=cmul(C2[1],w122); C2[2]=cmul(C2[2],w124);
    C2[3]=-C2[3];
    dft3<DIR>(C0[0],C1[0],C2[0], b[0],b[4],b[8]);
    dft3<DIR>(C0[1],C1[1],C2[1], b[1],b[5],b[9]);
    dft3<DIR>(C0[2],C1[2],C2[2], b[2],b[6],b[10]);
    dft3<DIR>(C0[3],C1[3],C2[3], b[3],b[7],b[11]);
}

// ============ h single-row path (b64, dbuf) ============

__device__ __forceinline__ void row_s1_fwd_h(const float* __restrict__ xa,
                                             v2f* __restrict__ bA, int tid)
{
    constexpr float STEP = -PI2 / 1920.0f;
    const v2f z = vmk(0.f,0.f);
    for (int p = tid; p < 240; p += 256) {
        v2f a[8], b[8];
        a[0]=z; a[1]=z; a[6]=z; a[7]=z;
        a[2] = vmk(xa[p],     0.f);
        a[3] = vmk(xa[p+240], 0.f);
        a[4] = vmk(xa[p+480], 0.f);
        a[5] = vmk(xa[p+720], 0.f);
        dft8<-1>(a,b);
        float sv, cv; __sincosf(STEP * (float)p, &sv, &cv);
        v2f w1 = vmk(cv, sv), w = w1;
        b[1] = cmul(b[1], w);
        #pragma unroll
        for (int u = 2; u < 8; ++u) { w = cmul(w, w1); b[u] = cmul(b[u], w); }
        #pragma unroll
        for (int u = 0; u < 8; ++u) bA[IDX(8*p + u)] = b[u];
    }
}

template<int DIR, int R, int NCUR, int S>
__device__ __forceinline__ void mid_stage(const v2f* __restrict__ src,
                                          v2f* __restrict__ dst, int tid)
{
    constexpr int M  = NCUR / R;
    constexpr int NB = M * S;
    constexpr float STEP = (float)DIR * PI2 / (float)NCUR;
    for (int i = tid; i < NB; i += 256) {
        const int p = i / S;
        v2f a[R], b[R];
        #pragma unroll
        for (int t = 0; t < R; ++t) a[t] = src[IDX(i + S*M*t)];
        if constexpr (R == 6) dft6<DIR>(a,b); else dft8<DIR>(a,b);
        float sv, cv; __sincosf(STEP * (float)p, &sv, &cv);
        v2f w1 = vmk(cv, sv), w = w1;
        b[1] = cmul(b[1], w);
        #pragma unroll
        for (int u = 2; u < R; ++u) { w = cmul(w, w1); b[u] = cmul(b[u], w); }
        const int ob = (i - p*S) + S*(R*p);
        #pragma unroll
        for (int u = 0; u < R; ++u) dst[IDX(ob + S*u)] = b[u];
    }
}

__device__ __forceinline__ void row_fin5_store_h(const v2f* __restrict__ src,
                                                 v2f* __restrict__ gdst, int tid)
{
    for (int q = tid; q < 384; q += 256) {
        v2f a[5], b[5];
        #pragma unroll
        for (int u = 0; u < 5; ++u) a[u] = src[IDX(q + 384*u)];
        dft5<-1>(a,b);
        #pragma unroll
        for (int u = 0; u < 5; ++u) gdst[q + 384*u] = b[u];
    }
}

// ============ row-pair path (float4, in-place) ============

__device__ __forceinline__ void rp_s1_fwd(const float* __restrict__ xa,
                                          const float* __restrict__ xb,
                                          float4* __restrict__ sb, int tid)
{
    constexpr float STEP = -PI2 / 1920.0f;
    const v2f z = vmk(0.f,0.f);
    for (int p = tid; p < 240; p += 256) {
        v2f a0[8], a1[8], b0[8], b1[8];
        a0[0]=a0[1]=a0[6]=a0[7]=z; a1[0]=a1[1]=a1[6]=a1[7]=z;
        #pragma unroll
        for (int t = 0; t < 4; ++t) {
            a0[2+t] = vmk(xa[p+240*t],     xb[p+240*t]);
            a1[2+t] = vmk(xa[960+p+240*t], xb[960+p+240*t]);
        }
        dft8<-1>(a0,b0); dft8<-1>(a1,b1);
        float sv, cv; __sincosf(STEP*(float)p, &sv, &cv);
        v2f w1 = vmk(cv,sv), w = w1;
        b0[1]=cmul(b0[1],w); b1[1]=cmul(b1[1],w);
        #pragma unroll
        for (int u = 2; u < 8; ++u){ w = cmul(w,w1); b0[u]=cmul(b0[u],w); b1[u]=cmul(b1[u],w); }
        #pragma unroll
        for (int u = 0; u < 8; ++u) st4(sb, 8*p+u, b0[u], b1[u]);
    }
}

__device__ __forceinline__ void rp_s1_inv(const v2f* __restrict__ Zr0,
                                          const v2f* __restrict__ Zr1,
                                          float4* __restrict__ sb, int tid)
{
    constexpr float STEP = PI2 / 1920.0f;
    for (int p = tid; p < 240; p += 256) {
        v2f a0[8], a1[8], b0[8], b1[8];
        #pragma unroll
        for (int t = 0; t < 8; ++t) { a0[t] = Zr0[p+240*t]; a1[t] = Zr1[p+240*t]; }
        dft8<1>(a0,b0); dft8<1>(a1,b1);
        float sv, cv; __sincosf(STEP*(float)p, &sv, &cv);
        v2f w1 = vmk(cv,sv), w = w1;
        b0[1]=cmul(b0[1],w); b1[1]=cmul(b1[1],w);
        #pragma unroll
        for (int u = 2; u < 8; ++u){ w = cmul(w,w1); b0[u]=cmul(b0[u],w); b1[u]=cmul(b1[u],w); }
        #pragma unroll
        for (int u = 0; u < 8; ++u) st4(sb, 8*p+u, b0[u], b1[u]);
    }
}

template<int DIR>
__device__ __forceinline__ void rp_mid8_ip(float4* __restrict__ sb, int tid)
{
    constexpr float STEP = (float)DIR * PI2 / 240.0f;
    const bool act = tid < 240;
    v2f b0[8], b1[8]; int ob = 0;
    if (act) {
        const int p = tid >> 3;
        v2f a0[8], a1[8];
        #pragma unroll
        for (int t = 0; t < 8; ++t) ld4(sb, tid + 240*t, a0[t], a1[t]);
        dft8<DIR>(a0,b0); dft8<DIR>(a1,b1);
        float sv, cv; __sincosf(STEP*(float)p, &sv, &cv);
        v2f w1 = vmk(cv,sv), w = w1;
        b0[1]=cmul(b0[1],w); b1[1]=cmul(b1[1],w);
        #pragma unroll
        for (int u = 2; u < 8; ++u){ w = cmul(w,w1); b0[u]=cmul(b0[u],w); b1[u]=cmul(b1[u],w); }
        ob = (tid - 8*p) + 64*p;
    }
    __syncthreads();
    if (act) {
        #pragma unroll
        for (int u = 0; u < 8; ++u) st4(sb, ob + 8*u, b0[u], b1[u]);
    }
    __syncthreads();
}

template<int DIR>
__device__ __forceinline__ void rp_mid6_ip(float4* __restrict__ sb, int tid)
{
    constexpr float STEP = (float)DIR * PI2 / 30.0f;
    v2f c0[6], c1[6], d0[6], d1[6]; int ob0, ob1 = 0;
    {
        const int i = tid, p = i >> 6;
        v2f a0[6], a1[6];
        #pragma unroll
        for (int t = 0; t < 6; ++t) ld4(sb, i + 320*t, a0[t], a1[t]);
        dft6<DIR>(a0,c0); dft6<DIR>(a1,c1);
        float sv, cv; __sincosf(STEP*(float)p, &sv, &cv);
        v2f w1 = vmk(cv,sv), w = w1;
        c0[1]=cmul(c0[1],w); c1[1]=cmul(c1[1],w);
        #pragma unroll
        for (int u = 2; u < 6; ++u){ w = cmul(w,w1); c0[u]=cmul(c0[u],w); c1[u]=cmul(c1[u],w); }
        ob0 = (i - 64*p) + 384*p;
    }
    const bool act2 = tid < 64;
    if (act2) {
        const int i = 256 + tid;                 // p = 4
        v2f a0[6], a1[6];
        #pragma unroll
        for (int t = 0; t < 6; ++t) ld4(sb, i + 320*t, a0[t], a1[t]);
        dft6<DIR>(a0,d0); dft6<DIR>(a1,d1);
        float sv, cv; __sincosf(STEP*4.0f, &sv, &cv);
        v2f w1 = vmk(cv,sv), w = w1;
        d0[1]=cmul(d0[1],w); d1[1]=cmul(d1[1],w);
        #pragma unroll
        for (int u = 2; u < 6; ++u){ w = cmul(w,w1); d0[u]=cmul(d0[u],w); d1[u]=cmul(d1[u],w); }
        ob1 = tid + 1536;
    }
    __syncthreads();
    {
        #pragma unroll
        for (int u = 0; u < 6; ++u) st4(sb, ob0 + 64*u, c0[u], c1[u]);
    }
    if (act2) {
        #pragma unroll
        for (int u = 0; u < 6; ++u) st4(sb, ob1 + 64*u, d0[u], d1[u]);
    }
    __syncthreads();
}

__device__ __forceinline__ void rp_fin5_storeZ(const float4* __restrict__ sb,
                                               v2f* __restrict__ Zr0,
                                               v2f* __restrict__ Zr1, int tid)
{
    for (int q = tid; q < 384; q += 256) {
        v2f a0[5],a1[5],b0[5],b1[5];
        #pragma unroll
        for (int u = 0; u < 5; ++u) ld4(sb, q + 384*u, a0[u], a1[u]);
        dft5<-1>(a0,b0); dft5<-1>(a1,b1);
        #pragma unroll
        for (int u = 0; u < 5; ++u) { Zr0[q+384*u] = b0[u]; Zr1[q+384*u] = b1[u]; }
    }
}

__device__ __forceinline__ void rp_fin5_crop(const float4* __restrict__ sb,
                                             float* __restrict__ oa0, float* __restrict__ ob0,
                                             float* __restrict__ oa1, float* __restrict__ ob1,
                                             int tid)
{
    for (int q = tid; q < 384; q += 256) {
        v2f a0[5],a1[5],b0[5],b1[5];
        #pragma unroll
        for (int u = 0; u < 5; ++u) ld4(sb, q + 384*u, a0[u], a1[u]);
        dft5<1>(a0,b0); dft5<1>(a1,b1);
        oa0[q+480] = b0[0].x; ob0[q+480] = b0[0].y;
        oa1[q+480] = b1[0].x; ob1[q+480] = b1[0].y;
        if (q < 96)   { oa0[q+864] = b0[1].x; ob0[q+864] = b0[1].y;
                        oa1[q+864] = b1[1].x; ob1[q+864] = b1[1].y; }
        if (q >= 288) { oa0[q-288] = b0[3].x; ob0[q-288] = b0[3].y;
                        oa1[q-288] = b1[3].x; ob1[q-288] = b1[3].y; }
        oa0[q+96]  = b0[4].x; ob0[q+96]  = b0[4].y;
        oa1[q+96]  = b1[4].x; ob1[q+96]  = b1[4].y;
    }
}

// ============ K2 column path (sincos, pair-per-thread, dbuf) ============

__device__ __forceinline__ void col_s1_fwd_pair(const v2f* __restrict__ g, int c0,
                                                v2f* __restrict__ bA, int tid)
{
    constexpr float STEP = -PI2 / 1080.0f;
    const v2f z = vmk(0.f,0.f);
    const float4* gc = (const float4*)(g + c0);
    for (int p = tid; p < 180; p += 256) {
        v2f a0[6], a1[6], b0[6], b1[6];
        a0[0]=a0[5]=a1[0]=a1[5]=z;
        if (p >= 90) { float4 t = gc[(p-90)*960]; a0[1]=vmk(t.x,t.y); a1[1]=vmk(t.z,t.w); }
        else         { a0[1]=a1[1]=z; }
        { float4 t = gc[(p+90)*960];  a0[2]=vmk(t.x,t.y); a1[2]=vmk(t.z,t.w); }
        { float4 t = gc[(p+270)*960]; a0[3]=vmk(t.x,t.y); a1[3]=vmk(t.z,t.w); }
        if (p < 90)  { float4 t = gc[(p+450)*960]; a0[4]=vmk(t.x,t.y); a1[4]=vmk(t.z,t.w); }
        else         { a0[4]=a1[4]=z; }
        dft6<-1>(a0,b0); dft6<-1>(a1,b1);
        float sv, cv; __sincosf(STEP*(float)p, &sv, &cv);
        v2f w1 = vmk(cv,sv), w = w1;
        b0[1]=cmul(b0[1],w); b1[1]=cmul(b1[1],w);
        #pragma unroll
        for (int u = 2; u < 6; ++u){ w = cmul(w,w1); b0[u]=cmul(b0[u],w); b1[u]=cmul(b1[u],w); }
        #pragma unroll
        for (int u = 0; u < 6; ++u) stp(bA, 6*p + u, b0[u], b1[u]);
    }
}

template<int DIR, int NCUR, int SC>
__device__ __forceinline__ void mid_pair(const v2f* __restrict__ src,
                                         v2f* __restrict__ dst, int tid)
{
    constexpr int NB = 180;
    constexpr float STEP = (float)DIR * PI2 / (float)NCUR;
    for (int ic = tid; ic < NB; ic += 256) {
        const int p = ic / SC;
        v2f a0[6], a1[6], b0[6], b1[6];
        #pragma unroll
        for (int t = 0; t < 6; ++t) ldp(src, ic + NB*t, a0[t], a1[t]);
        dft6<DIR>(a0,b0); dft6<DIR>(a1,b1);
        float sv, cv; __sincosf(STEP*(float)p, &sv, &cv);
        v2f w1 = vmk(cv,sv), w = w1;
        b0[1]=cmul(b0[1],w); b1[1]=cmul(b1[1],w);
        #pragma unroll
        for (int u = 2; u < 6; ++u){ w = cmul(w,w1); b0[u]=cmul(b0[u],w); b1[u]=cmul(b1[u],w); }
        const int ob = (ic - p*SC) + SC*6*p;
        #pragma unroll
        for (int u = 0; u < 6; ++u) stp(dst, ob + SC*u, b0[u], b1[u]);
    }
}

// ============ K4 B=4 high-radix in-place pieces ============

__device__ __forceinline__ void c4_s1_fwd10(const v2f* __restrict__ Zp, int c0,
                                            float4* __restrict__ sb, int tid)
{
    constexpr float STEP = -PI2 / 1080.0f;
    const v2f z = vmk(0.f,0.f);
    const float4* gc = (const float4*)(Zp + c0);
    const bool act = tid < 216;
    if (act) {
        const int g = tid & 1, p = tid >> 1;
        v2f a0[10], a1[10], b0[10], b1[10];
        a0[0]=a0[1]=a0[8]=a0[9]=z; a1[0]=a1[1]=a1[8]=a1[9]=z;
        if (p >= 54) { float4 t = gc[(p-54)*960+g]; a0[2]=vmk(t.x,t.y); a1[2]=vmk(t.z,t.w); }
        else         { a0[2]=a1[2]=z; }
        { float4 t = gc[(p+54)*960+g];  a0[3]=vmk(t.x,t.y); a1[3]=vmk(t.z,t.w); }
        { float4 t = gc[(p+162)*960+g]; a0[4]=vmk(t.x,t.y); a1[4]=vmk(t.z,t.w); }
        { float4 t = gc[(p+270)*960+g]; a0[5]=vmk(t.x,t.y); a1[5]=vmk(t.z,t.w); }
        { float4 t = gc[(p+378)*960+g]; a0[6]=vmk(t.x,t.y); a1[6]=vmk(t.z,t.w); }
        if (p < 54)  { float4 t = gc[(p+486)*960+g]; a0[7]=vmk(t.x,t.y); a1[7]=vmk(t.z,t.w); }
        else         { a0[7]=a1[7]=z; }
        dft10<-1>(a0,b0); dft10<-1>(a1,b1);
        float sv, cv; __sincosf(STEP*(float)p, &sv, &cv);
        v2f w1 = vmk(cv,sv), w = w1;
        b0[1]=cmul(b0[1],w); b1[1]=cmul(b1[1],w);
        #pragma unroll
        for (int u = 2; u < 10; ++u){ w = cmul(w,w1); b0[u]=cmul(b0[u],w); b1[u]=cmul(b1[u],w); }
        #pragma unroll
        for (int u = 0; u < 10; ++u) st4g(sb, 10*p+u, g, b0[u], b1[u]);
    }
    __syncthreads();
}

template<int DIR, int NCUR, int SC>
__device__ __forceinline__ void c4_mid12_ip(float4* __restrict__ sb, int tid)
{
    constexpr int NB = (NCUR/12)*SC;   // 90
    constexpr float STEP = (float)DIR * PI2 / (float)NCUR;
    const bool act = tid < 2*NB;
    v2f b0[12], b1[12]; int ob = 0, g = 0;
    if (act) {
        g = tid & 1;
        const int ic = tid >> 1;
        const int p = ic / SC;
        v2f a0[12], a1[12];
        #pragma unroll
        for (int t = 0; t < 12; ++t) ld4g(sb, ic + NB*t, g, a0[t], a1[t]);
        dft12<DIR>(a0,b0); dft12<DIR>(a1,b1);
        float sv, cv; __sincosf(STEP*(float)p, &sv, &cv);
        v2f w1 = vmk(cv,sv), w = w1;
        b0[1]=cmul(b0[1],w); b1[1]=cmul(b1[1],w);
        #pragma unroll
        for (int u = 2; u < 12; ++u){ w = cmul(w,w1); b0[u]=cmul(b0[u],w); b1[u]=cmul(b1[u],w); }
        ob = (ic - p*SC) + SC*12*p;
    }
    __syncthreads();
    if (act) {
        #pragma unroll
        for (int u = 0; u < 12; ++u) st4g(sb, ob + SC*u, g, b0[u], b1[u]);
    }
    __syncthreads();
}

__device__ __forceinline__ void c4_f9K9_ip(float4* __restrict__ sb,
                                           const float4* __restrict__ KI,
                                           int cg, int tid)
{
    constexpr float STEP = PI2 / 1080.0f;
    const bool act = tid < 240;
    v2f d0[9], d1[9]; int q = 0, g = 0;
    if (act) {
        g = tid & 1; q = tid >> 1;
        const float4* Kc = KI + (cg*2 + g)*1080;
        v2f a0[9], a1[9], s0[9], s1[9];
        #pragma unroll
        for (int u = 0; u < 9; ++u) ld4g(sb, q + 120*u, g, a0[u], a1[u]);
        dft9<-1>(a0,s0); dft9<-1>(a1,s1);
        #pragma unroll
        for (int u = 0; u < 9; ++u) {
            float4 kk = Kc[q + 120*u];
            s0[u] = cmul(s0[u], vmk(kk.x,kk.y));
            s1[u] = cmul(s1[u], vmk(kk.z,kk.w));
        }
        dft9<1>(s0,d0); dft9<1>(s1,d1);
        float sv, cv; __sincosf(STEP*(float)q, &sv, &cv);
        v2f w1 = vmk(cv,sv), w = w1;
        d0[1]=cmul(d0[1],w); d1[1]=cmul(d1[1],w);
        #pragma unroll
        for (int u = 2; u < 9; ++u){ w = cmul(w,w1); d0[u]=cmul(d0[u],w); d1[u]=cmul(d1[u],w); }
    }
    __syncthreads();
    if (act) {
        #pragma unroll
        for (int u = 0; u < 9; ++u) st4g(sb, 9*q + u, g, d0[u], d1[u]);
    }
    __syncthreads();
}

__device__ __forceinline__ void c4_fin10_crop(const float4* __restrict__ sb,
                                              v2f* __restrict__ Zp,
                                              int c0, int tid)
{
    const bool act = tid < 216;
    if (!act) return;
    const int g = tid & 1, q = tid >> 1;
    float4* gc = (float4*)(Zp + c0);
    v2f a0[10], a1[10], b0[10], b1[10];
    #pragma unroll
    for (int u = 0; u < 10; ++u) ld4g(sb, q + 108*u, g, a0[u], a1[u]);
    dft10<1>(a0,b0); dft10<1>(a1,b1);
    gc[(q+270)*960+g] = pk(b0[0], b1[0]);
    gc[(q+378)*960+g] = pk(b0[1], b1[1]);
    if (q < 54)  gc[(q+486)*960+g] = pk(b0[2], b1[2]);
    if (q >= 54) gc[(q-54)*960+g]  = pk(b0[7], b1[7]);
    gc[(q+54)*960+g]  = pk(b0[8], b1[8]);
    gc[(q+162)*960+g] = pk(b0[9], b1[9]);
}

// ============ kernels ============

// K13: row forward FFTs. Blocks [0,1080): x pairs; [1080,1620): h rows.
__global__ __launch_bounds__(256,5) void k_row_fwd(const float* __restrict__ x,
                                                   const float* __restrict__ h,
                                                   v2f* __restrict__ Z,
                                                   v2f* __restrict__ Hrow)
{
    __shared__ float4 sb[IDX4SZ(1920)];
    const int tid = threadIdx.x;
    if (blockIdx.x < 1080) {
        const int pp = blockIdx.x / 270;
        const int r0 = (blockIdx.x % 270) * 2;
        const float* xa = x + ((2*pp  )*540 + r0)*960;
        const float* xb = x + ((2*pp+1)*540 + r0)*960;
        rp_s1_fwd(xa, xb, sb, tid); __syncthreads();
        rp_mid8_ip<-1>(sb, tid);
        rp_mid6_ip<-1>(sb, tid);
        v2f* Zr0 = Z + (pp*540 + r0)*1920;
        rp_fin5_storeZ(sb, Zr0, Zr0 + 1920, tid);
    } else {
        v2f* bA = (v2f*)sb;
        v2f* bB = bA + IDXSZ(1920);
        const int r = blockIdx.x - 1080;
        row_s1_fwd_h(h + r*960, bA, tid); __syncthreads();
        mid_stage<-1,8,240, 8>(bA, bB, tid); __syncthreads();
        mid_stage<-1,6, 30,64>(bB, bA, tid); __syncthreads();
        row_fin5_store_h(bA, Hrow + r*1920, tid);
    }
}

// K2: column FFTs of Hrow (pair/thread, dbuf) + build pair-interleaved KI.
__global__ __launch_bounds__(256,4) void k_col_fft_h_buildK(const v2f* __restrict__ Hrow,
                                                            const float* __restrict__ mu1,
                                                            float4* __restrict__ KI)
{
    __shared__ v2f bA[IDXPSZ(2160)], bB[IDXPSZ(2160)];
    const int tid = threadIdx.x;
    const int xcd = blockIdx.x & 7, idx = blockIdx.x >> 3;
    const int cpair = xcd*120 + idx, c0 = cpair*2;
    col_s1_fwd_pair(Hrow, c0, bA, tid);  __syncthreads();
    mid_pair<-1,180, 6>(bA, bB, tid);    __syncthreads();
    mid_pair<-1, 30,36>(bB, bA, tid);    __syncthreads();
    const float sc = mu1[4] / ((1.0f + 1e-6f) * 2073600.0f);
    const float cos0 = __cosf(PI2 * (float)(c0  ) * (1.0f/1920.0f));
    const float cos1 = __cosf(PI2 * (float)(c0+1) * (1.0f/1920.0f));
    float4* Kc = KI + cpair*1080;
    for (int p = tid; p < 216; p += 256) {
        v2f a0[5],a1[5],b0[5],b1[5];
        #pragma unroll
        for (int u = 0; u < 5; ++u) ldp(bA, p + 216*u, a0[u], a1[u]);
        dft5<-1>(a0,b0); dft5<-1>(a1,b1);
        #pragma unroll
        for (int u = 0; u < 5; ++u) {
            const int k = p + 216*u;
            const float cosk = __cosf(PI2 * (float)k * (1.0f/1080.0f));
            float m0 = b0[u].x*b0[u].x + b0[u].y*b0[u].y;
            float m1 = b1[u].x*b1[u].x + b1[u].y*b1[u].y;
            float f0 = sc / (1e-6f*m0 + 1e-5f*(4.0f - 2.0f*cosk - 2.0f*cos0) + 4e-5f);
            float f1 = sc / (1e-6f*m1 + 1e-5f*(4.0f - 2.0f*cosk - 2.0f*cos1) + 4e-5f);
            Kc[k] = make_float4(f0*b0[u].x, -f0*b0[u].y, f1*b1[u].x, -f1*b1[u].y);
        }
    }
}

// K4: B=4 columns/block, radix {10,12,[9 K 9],12,10}, IN-PLACE (36.7KB LDS,
// 4 blocks/CU). Grid 1920; XCD swizzle.
__global__ __launch_bounds__(256,4) void k_col_fused(v2f* __restrict__ Z,
                                                     const float4* __restrict__ KI)
{
    __shared__ float4 sb[IDX4SZ(2160)];
    const int tid = threadIdx.x;
    const int xcd = blockIdx.x & 7, idx = blockIdx.x >> 3;   // idx in [0,240)
    const int pp  = idx / 60;
    const int cg  = xcd*60 + (idx - pp*60);                  // col-group [0,480)
    const int c0  = cg*4;
    v2f* Zp = Z + pp*540*1920;
    c4_s1_fwd10(Zp, c0, sb, tid);
    c4_mid12_ip<-1,108,10>(sb, tid);
    c4_f9K9_ip(sb, KI, cg, tid);
    c4_mid12_ip< 1,120, 9>(sb, tid);
    c4_fin10_crop(sb, Zp, c0, tid);
}

// K5: row inverse FFTs, paired rows + crop + split into real outputs.
__global__ __launch_bounds__(256,5) void k_row_inv_out(const v2f* __restrict__ Z,
                                                       float* __restrict__ out)
{
    __shared__ float4 sb[IDX4SZ(1920)];
    const int tid = threadIdx.x;
    const int pp = blockIdx.x / 270;
    const int r0 = (blockIdx.x % 270) * 2;
    const v2f* Zr0 = Z + (pp*540 + r0)*1920;
    rp_s1_inv(Zr0, Zr0 + 1920, sb, tid); __syncthreads();
    rp_mid8_ip<1>(sb, tid);
    rp_mid6_ip<1>(sb, tid);
    float* oa0 = out + ((2*pp  )*540 + r0)*960;
    float* ob0 = out + ((2*pp+1)*540 + r0)*960;
    rp_fin5_crop(sb, oa0, ob0, oa0 + 960, ob0 + 960, tid);
}

extern "C" void kernel_launch(void* const* d_in, const int* in_sizes, int n_in,
                              void* d_out, int out_size, void* d_ws, size_t ws_size,
                              hipStream_t stream)
{
    (void)in_sizes; (void)n_in; (void)out_size; (void)ws_size;
    const float* x   = (const float*)d_in[0];
    const float* h   = (const float*)d_in[1];
    const float* mu1 = (const float*)d_in[2];
    float*       out = (float*)d_out;

    // ws layout: KI (960*1080 f4 = 16.6MB) | Z (4*540*1920 v2f = 33.2MB) |
    // Hrow (540*1920 v2f = 8.3MB).
    float4* KI   = (float4*)d_ws;
    v2f*    Z    = (v2f*)(KI + 960*1080);
    v2f*    Hrow = Z + 4*540*1920;

    k_row_fwd         <<<1620,   256, 0, stream>>>(x, h, Z, Hrow);
    k_col_fft_h_buildK<<<960,    256, 0, stream>>>(Hrow, mu1, KI);
    k_col_fused       <<<1920,   256, 0, stream>>>(Z, KI);
    k_row_inv_out     <<<1080,   256, 0, stream>>>(Z, out);
}

// Round 15
// 72.886 us; speedup vs baseline: 1.1065x; 1.0115x over previous
//
#include <hip/hip_runtime.h>

// Le-ADMM reduction: state resets each iteration => output is one linear
// circular filter: out = crop_shift( IFFT2( K . FFT2(pad(x)) ) ),
// K = mu1[4]/((1+1e-6)*FH*FW) * conj(Hp) / (1e-6|Hp|^2 + 1e-5*PsiTPsi + 4e-5).
// Pairs packed z = x_a + i*x_b (K Hermitian => both results real).
//
// R14: TREE TWIDDLES. Same config as R13 (=R11 best, 73.7us): packed v2f
// math, paired rows 8*8*6*5 in-place, K4 B=4 radix-{10,12,[9K9],12,10}
// in-place, XCD swizzle. Single change: twiddle powers w^u computed by
// log-depth tree (w^u = w^(u/2)*w^(u-u/2)) instead of the serial
// w = cmul(w,w1) chain -- same op count, critical path 10->4 (radix-12),
// and all b[u] twiddle-multiplies become independent. Attacks the ~50%
// VALUBusy latency gap at 4-8 blocks/CU occupancy.

#define PI2 6.2831853071795864f

typedef float v2f __attribute__((ext_vector_type(2)));

__device__ __forceinline__ v2f vmk(float x, float y){ v2f r; r.x = x; r.y = y; return r; }
__device__ __forceinline__ v2f cmul(v2f a, v2f b){
    return vmk(a.x, a.x)*b + vmk(-a.y, a.y)*vmk(b.y, b.x);
}
__device__ __forceinline__ float4 pk(v2f a, v2f b){ return make_float4(a.x,a.y,b.x,b.y); }

// Tree-structured twiddle powers: w[u-1] = w1^u, depth O(log R).
template<int R>
__device__ __forceinline__ void twpow(v2f w1, v2f* __restrict__ w){
    w[0] = w1;
    #pragma unroll
    for (int u = 2; u < R; ++u) w[u-1] = cmul(w[u/2 - 1], w[(u - u/2) - 1]);
}

// b64 pad (h single-row path): +1 v2f per 16.
__device__ __forceinline__ int IDX(int a){ return a + (a >> 4); }
#define IDXSZ(n) ((n) + ((n) >> 4))
// K2 v2f pad: +2 per 32 (float4-aligned).
__device__ __forceinline__ int IDXP(int a){ return a + ((a >> 5) << 1); }
#define IDXPSZ(n) ((n) + (((n) >> 5) << 1) + 4)
// float4-slot pad: +1 slot per 16.
__device__ __forceinline__ int IDX4(int a){ return a + (a >> 4); }
#define IDX4SZ(n) ((n) + ((n) >> 4) + 2)

// K2 pair LDS (v2f buffer, float4 access).
__device__ __forceinline__ void ldp(const v2f* __restrict__ b, int pos,
                                    v2f& v0, v2f& v1){
    const float4 t = *(const float4*)&b[IDXP(2*pos)];
    v0 = vmk(t.x,t.y); v1 = vmk(t.z,t.w);
}
__device__ __forceinline__ void stp(v2f* __restrict__ b, int pos,
                                    v2f v0, v2f v1){
    *(float4*)&b[IDXP(2*pos)] = pk(v0, v1);
}
// Row-pair LDS (float4 buffer).
__device__ __forceinline__ void ld4(const float4* __restrict__ b, int pos,
                                    v2f& v0, v2f& v1){
    const float4 t = b[IDX4(pos)];
    v0 = vmk(t.x,t.y); v1 = vmk(t.z,t.w);
}
__device__ __forceinline__ void st4(float4* __restrict__ b, int pos,
                                    v2f v0, v2f v1){
    b[IDX4(pos)] = pk(v0, v1);
}
// K4 B=4 LDS: slot = 2*pos + g (g = pair group 0/1).
__device__ __forceinline__ void ld4g(const float4* __restrict__ b, int pos, int g,
                                     v2f& v0, v2f& v1){
    const float4 t = b[IDX4(2*pos+g)];
    v0 = vmk(t.x,t.y); v1 = vmk(t.z,t.w);
}
__device__ __forceinline__ void st4g(float4* __restrict__ b, int pos, int g,
                                     v2f v0, v2f v1){
    b[IDX4(2*pos+g)] = pk(v0, v1);
}

template<int DIR>
__device__ __forceinline__ void dft3(v2f x0, v2f x1, v2f x2,
                                     v2f& y0, v2f& y1, v2f& y2)
{
    constexpr float s3 = (float)DIR * 0.8660254037844386f;
    v2f t = x1 + x2, u = x1 - x2;
    v2f m = x0 - 0.5f*t;
    v2f iu = vmk(-s3*u.y, s3*u.x);
    y0 = x0 + t; y1 = m + iu; y2 = m - iu;
}

template<int DIR>
__device__ __forceinline__ void dft4(v2f a0, v2f a1, v2f a2, v2f a3,
                                     v2f& b0, v2f& b1, v2f& b2, v2f& b3)
{
    v2f t0 = a0+a2, t1 = a0-a2, t2 = a1+a3, t3 = a1-a3;
    v2f j3 = vmk(-(float)DIR*t3.y, (float)DIR*t3.x);
    b0 = t0+t2; b2 = t0-t2; b1 = t1+j3; b3 = t1-j3;
}

template<int DIR>
__device__ __forceinline__ void dft6(const v2f a[6], v2f b[6])
{
    v2f e0,e1,e2,o0,o1,o2;
    dft3<DIR>(a[0],a[2],a[4], e0,e1,e2);
    dft3<DIR>(a[1],a[3],a[5], o0,o1,o2);
    constexpr float s3 = (float)DIR * 0.8660254037844386f;
    const v2f w1 = vmk( 0.5f, s3);
    const v2f w2 = vmk(-0.5f, s3);
    v2f t1 = cmul(w1,o1), t2 = cmul(w2,o2);
    b[0]=e0+o0; b[3]=e0-o0;
    b[1]=e1+t1; b[4]=e1-t1;
    b[2]=e2+t2; b[5]=e2-t2;
}

template<int DIR>
__device__ __forceinline__ void dft8(const v2f a[8], v2f b[8])
{
    v2f e0,e1,e2,e3,o0,o1,o2,o3;
    dft4<DIR>(a[0],a[2],a[4],a[6], e0,e1,e2,e3);
    dft4<DIR>(a[1],a[3],a[5],a[7], o0,o1,o2,o3);
    constexpr float c = 0.70710678118654752f;
    const v2f w1 = vmk( c, (float)DIR*c);
    const v2f w3 = vmk(-c, (float)DIR*c);
    v2f t1 = cmul(w1,o1);
    v2f t2 = vmk(-(float)DIR*o2.y, (float)DIR*o2.x);
    v2f t3 = cmul(w3,o3);
    b[0]=e0+o0; b[4]=e0-o0;
    b[1]=e1+t1; b[5]=e1-t1;
    b[2]=e2+t2; b[6]=e2-t2;
    b[3]=e3+t3; b[7]=e3-t3;
}

template<int DIR>
__device__ __forceinline__ void dft5(const v2f a[5], v2f b[5])
{
    constexpr float C1 = 0.30901699437494742f, S1c = 0.9510565162951535f;
    constexpr float C2 = -0.8090169943749475f, S2c = 0.5877852522924731f;
    v2f t1 = a[1]+a[4], t2 = a[2]+a[3], d1 = a[1]-a[4], d2 = a[2]-a[3];
    v2f m1 = a[0] + C1*t1 + C2*t2;
    v2f m2 = a[0] + C2*t1 + C1*t2;
    v2f e1 = S1c*d1 + S2c*d2;
    v2f e2 = S2c*d1 - S1c*d2;
    v2f ie1 = vmk(-(float)DIR*e1.y, (float)DIR*e1.x);
    v2f ie2 = vmk(-(float)DIR*e2.y, (float)DIR*e2.x);
    b[0] = a[0] + t1 + t2;
    b[1] = m1+ie1; b[4] = m1-ie1;
    b[2] = m2+ie2; b[3] = m2-ie2;
}

// dft9 / dft10 / dft12 (structure verified R6/R10).
template<int DIR>
__device__ __forceinline__ void dft9(const v2f a[9], v2f b[9])
{
    v2f C0[3], C1[3], C2[3];
    dft3<DIR>(a[0],a[3],a[6], C0[0],C0[1],C0[2]);
    dft3<DIR>(a[1],a[4],a[7], C1[0],C1[1],C1[2]);
    dft3<DIR>(a[2],a[5],a[8], C2[0],C2[1],C2[2]);
    const v2f w91 = vmk(0.7660444431189780f, (float)DIR*0.6427876096865393f);
    const v2f w92 = vmk(0.1736481776669304f, (float)DIR*0.9848077530122081f);
    const v2f w94 = vmk(-0.9396926207859084f, (float)DIR*0.3420201433256687f);
    C1[1]=cmul(C1[1],w91); C1[2]=cmul(C1[2],w92);
    C2[1]=cmul(C2[1],w92); C2[2]=cmul(C2[2],w94);
    dft3<DIR>(C0[0],C1[0],C2[0], b[0],b[3],b[6]);
    dft3<DIR>(C0[1],C1[1],C2[1], b[1],b[4],b[7]);
    dft3<DIR>(C0[2],C1[2],C2[2], b[2],b[5],b[8]);
}

template<int DIR>
__device__ __forceinline__ void dft10(const v2f a[10], v2f b[10])
{
    v2f ae[5] = {a[0],a[2],a[4],a[6],a[8]};
    v2f ao[5] = {a[1],a[3],a[5],a[7],a[9]};
    v2f E[5], O[5];
    dft5<DIR>(ae, E); dft5<DIR>(ao, O);
    const v2f w1 = vmk( 0.8090169943749475f, (float)DIR*0.5877852522924731f);
    const v2f w2 = vmk( 0.3090169943749474f, (float)DIR*0.9510565162951535f);
    const v2f w3 = vmk(-0.3090169943749474f, (float)DIR*0.9510565162951535f);
    const v2f w4 = vmk(-0.8090169943749475f, (float)DIR*0.5877852522924731f);
    v2f t1 = cmul(O[1],w1), t2 = cmul(O[2],w2), t3 = cmul(O[3],w3), t4 = cmul(O[4],w4);
    b[0]=E[0]+O[0]; b[5]=E[0]-O[0];
    b[1]=E[1]+t1;   b[6]=E[1]-t1;
    b[2]=E[2]+t2;   b[7]=E[2]-t2;
    b[3]=E[3]+t3;   b[8]=E[3]-t3;
    b[4]=E[4]+t4;   b[9]=E[4]-t4;
}

template<int DIR>
__device__ __forceinline__ void dft12(const v2f a[12], v2f b[12])
{
    v2f C0[4], C1[4], C2[4];
    dft4<DIR>(a[0],a[3],a[6],a[9],  C0[0],C0[1],C0[2],C0[3]);
    dft4<DIR>(a[1],a[4],a[7],a[10], C1[0],C1[1],C1[2],C1[3]);
    dft4<DIR>(a[2],a[5],a[8],a[11], C2[0],C2[1],C2[2],C2[3]);
    const v2f w121 = vmk(0.8660254037844386f, (float)DIR*0.5f);
    const v2f w122 = vmk(0.5f, (float)DIR*0.8660254037844386f);
    const v2f w124 = vmk(-0.5f, (float)DIR*0.8660254037844386f);
    C1[1]=cmul(C1[1],w121); C1[2]=cmul(C1[2],w122);
    C1[3]=vmk(-(float)DIR*C1[3].y, (float)DIR*C1[3].x);
    C2[1]=cmul(C2[1],w122); C2[2]=cmul(C2[2],w124);
    C2[3]=-C2[3];
    dft3<DIR>(C0[0],C1[0],C2[0], b[0],b[4],b[8]);
    dft3<DIR>(C0[1],C1[1],C2[1], b[1],b[5],b[9]);
    dft3<DIR>(C0[2],C1[2],C2[2], b[2],b[6],b[10]);
    dft3<DIR>(C0[3],C1[3],C2[3], b[3],b[7],b[11]);
}

// ============ h single-row path (b64, dbuf) ============

__device__ __forceinline__ void row_s1_fwd_h(const float* __restrict__ xa,
                                             v2f* __restrict__ bA, int tid)
{
    constexpr float STEP = -PI2 / 1920.0f;
    const v2f z = vmk(0.f,0.f);
    for (int p = tid; p < 240; p += 256) {
        v2f a[8], b[8];
        a[0]=z; a[1]=z; a[6]=z; a[7]=z;
        a[2] = vmk(xa[p],     0.f);
        a[3] = vmk(xa[p+240], 0.f);
        a[4] = vmk(xa[p+480], 0.f);
        a[5] = vmk(xa[p+720], 0.f);
        dft8<-1>(a,b);
        float sv, cv; __sincosf(STEP * (float)p, &sv, &cv);
        v2f w[7]; twpow<8>(vmk(cv, sv), w);
        #pragma unroll
        for (int u = 1; u < 8; ++u) b[u] = cmul(b[u], w[u-1]);
        #pragma unroll
        for (int u = 0; u < 8; ++u) bA[IDX(8*p + u)] = b[u];
    }
}

template<int DIR, int R, int NCUR, int S>
__device__ __forceinline__ void mid_stage(const v2f* __restrict__ src,
                                          v2f* __restrict__ dst, int tid)
{
    constexpr int M  = NCUR / R;
    constexpr int NB = M * S;
    constexpr float STEP = (float)DIR * PI2 / (float)NCUR;
    for (int i = tid; i < NB; i += 256) {
        const int p = i / S;
        v2f a[R], b[R];
        #pragma unroll
        for (int t = 0; t < R; ++t) a[t] = src[IDX(i + S*M*t)];
        if constexpr (R == 6) dft6<DIR>(a,b); else dft8<DIR>(a,b);
        float sv, cv; __sincosf(STEP * (float)p, &sv, &cv);
        v2f w[R-1]; twpow<R>(vmk(cv, sv), w);
        #pragma unroll
        for (int u = 1; u < R; ++u) b[u] = cmul(b[u], w[u-1]);
        const int ob = (i - p*S) + S*(R*p);
        #pragma unroll
        for (int u = 0; u < R; ++u) dst[IDX(ob + S*u)] = b[u];
    }
}

__device__ __forceinline__ void row_fin5_store_h(const v2f* __restrict__ src,
                                                 v2f* __restrict__ gdst, int tid)
{
    for (int q = tid; q < 384; q += 256) {
        v2f a[5], b[5];
        #pragma unroll
        for (int u = 0; u < 5; ++u) a[u] = src[IDX(q + 384*u)];
        dft5<-1>(a,b);
        #pragma unroll
        for (int u = 0; u < 5; ++u) gdst[q + 384*u] = b[u];
    }
}

// ============ row-pair path (float4, in-place) ============

__device__ __forceinline__ void rp_s1_fwd(const float* __restrict__ xa,
                                          const float* __restrict__ xb,
                                          float4* __restrict__ sb, int tid)
{
    constexpr float STEP = -PI2 / 1920.0f;
    const v2f z = vmk(0.f,0.f);
    for (int p = tid; p < 240; p += 256) {
        v2f a0[8], a1[8], b0[8], b1[8];
        a0[0]=a0[1]=a0[6]=a0[7]=z; a1[0]=a1[1]=a1[6]=a1[7]=z;
        #pragma unroll
        for (int t = 0; t < 4; ++t) {
            a0[2+t] = vmk(xa[p+240*t],     xb[p+240*t]);
            a1[2+t] = vmk(xa[960+p+240*t], xb[960+p+240*t]);
        }
        dft8<-1>(a0,b0); dft8<-1>(a1,b1);
        float sv, cv; __sincosf(STEP*(float)p, &sv, &cv);
        v2f w[7]; twpow<8>(vmk(cv,sv), w);
        #pragma unroll
        for (int u = 1; u < 8; ++u){ b0[u]=cmul(b0[u],w[u-1]); b1[u]=cmul(b1[u],w[u-1]); }
        #pragma unroll
        for (int u = 0; u < 8; ++u) st4(sb, 8*p+u, b0[u], b1[u]);
    }
}

__device__ __forceinline__ void rp_s1_inv(const v2f* __restrict__ Zr0,
                                          const v2f* __restrict__ Zr1,
                                          float4* __restrict__ sb, int tid)
{
    constexpr float STEP = PI2 / 1920.0f;
    for (int p = tid; p < 240; p += 256) {
        v2f a0[8], a1[8], b0[8], b1[8];
        #pragma unroll
        for (int t = 0; t < 8; ++t) { a0[t] = Zr0[p+240*t]; a1[t] = Zr1[p+240*t]; }
        dft8<1>(a0,b0); dft8<1>(a1,b1);
        float sv, cv; __sincosf(STEP*(float)p, &sv, &cv);
        v2f w[7]; twpow<8>(vmk(cv,sv), w);
        #pragma unroll
        for (int u = 1; u < 8; ++u){ b0[u]=cmul(b0[u],w[u-1]); b1[u]=cmul(b1[u],w[u-1]); }
        #pragma unroll
        for (int u = 0; u < 8; ++u) st4(sb, 8*p+u, b0[u], b1[u]);
    }
}

template<int DIR>
__device__ __forceinline__ void rp_mid8_ip(float4* __restrict__ sb, int tid)
{
    constexpr float STEP = (float)DIR * PI2 / 240.0f;
    const bool act = tid < 240;
    v2f b0[8], b1[8]; int ob = 0;
    if (act) {
        const int p = tid >> 3;
        v2f a0[8], a1[8];
        #pragma unroll
        for (int t = 0; t < 8; ++t) ld4(sb, tid + 240*t, a0[t], a1[t]);
        dft8<DIR>(a0,b0); dft8<DIR>(a1,b1);
        float sv, cv; __sincosf(STEP*(float)p, &sv, &cv);
        v2f w[7]; twpow<8>(vmk(cv,sv), w);
        #pragma unroll
        for (int u = 1; u < 8; ++u){ b0[u]=cmul(b0[u],w[u-1]); b1[u]=cmul(b1[u],w[u-1]); }
        ob = (tid - 8*p) + 64*p;
    }
    __syncthreads();
    if (act) {
        #pragma unroll
        for (int u = 0; u < 8; ++u) st4(sb, ob + 8*u, b0[u], b1[u]);
    }
    __syncthreads();
}

template<int DIR>
__device__ __forceinline__ void rp_mid6_ip(float4* __restrict__ sb, int tid)
{
    constexpr float STEP = (float)DIR * PI2 / 30.0f;
    v2f c0[6], c1[6], d0[6], d1[6]; int ob0, ob1 = 0;
    {
        const int i = tid, p = i >> 6;
        v2f a0[6], a1[6];
        #pragma unroll
        for (int t = 0; t < 6; ++t) ld4(sb, i + 320*t, a0[t], a1[t]);
        dft6<DIR>(a0,c0); dft6<DIR>(a1,c1);
        float sv, cv; __sincosf(STEP*(float)p, &sv, &cv);
        v2f w[5]; twpow<6>(vmk(cv,sv), w);
        #pragma unroll
        for (int u = 1; u < 6; ++u){ c0[u]=cmul(c0[u],w[u-1]); c1[u]=cmul(c1[u],w[u-1]); }
        ob0 = (i - 64*p) + 384*p;
    }
    const bool act2 = tid < 64;
    if (act2) {
        const int i = 256 + tid;                 // p = 4
        v2f a0[6], a1[6];
        #pragma unroll
        for (int t = 0; t < 6; ++t) ld4(sb, i + 320*t, a0[t], a1[t]);
        dft6<DIR>(a0,d0); dft6<DIR>(a1,d1);
        float sv, cv; __sincosf(STEP*4.0f, &sv, &cv);
        v2f w[5]; twpow<6>(vmk(cv,sv), w);
        #pragma unroll
        for (int u = 1; u < 6; ++u){ d0[u]=cmul(d0[u],w[u-1]); d1[u]=cmul(d1[u],w[u-1]); }
        ob1 = tid + 1536;
    }
    __syncthreads();
    {
        #pragma unroll
        for (int u = 0; u < 6; ++u) st4(sb, ob0 + 64*u, c0[u], c1[u]);
    }
    if (act2) {
        #pragma unroll
        for (int u = 0; u < 6; ++u) st4(sb, ob1 + 64*u, d0[u], d1[u]);
    }
    __syncthreads();
}

__device__ __forceinline__ void rp_fin5_storeZ(const float4* __restrict__ sb,
                                               v2f* __restrict__ Zr0,
                                               v2f* __restrict__ Zr1, int tid)
{
    for (int q = tid; q < 384; q += 256) {
        v2f a0[5],a1[5],b0[5],b1[5];
        #pragma unroll
        for (int u = 0; u < 5; ++u) ld4(sb, q + 384*u, a0[u], a1[u]);
        dft5<-1>(a0,b0); dft5<-1>(a1,b1);
        #pragma unroll
        for (int u = 0; u < 5; ++u) { Zr0[q+384*u] = b0[u]; Zr1[q+384*u] = b1[u]; }
    }
}

__device__ __forceinline__ void rp_fin5_crop(const float4* __restrict__ sb,
                                             float* __restrict__ oa0, float* __restrict__ ob0,
                                             float* __restrict__ oa1, float* __restrict__ ob1,
                                             int tid)
{
    for (int q = tid; q < 384; q += 256) {
        v2f a0[5],a1[5],b0[5],b1[5];
        #pragma unroll
        for (int u = 0; u < 5; ++u) ld4(sb, q + 384*u, a0[u], a1[u]);
        dft5<1>(a0,b0); dft5<1>(a1,b1);
        oa0[q+480] = b0[0].x; ob0[q+480] = b0[0].y;
        oa1[q+480] = b1[0].x; ob1[q+480] = b1[0].y;
        if (q < 96)   { oa0[q+864] = b0[1].x; ob0[q+864] = b0[1].y;
                        oa1[q+864] = b1[1].x; ob1[q+864] = b1[1].y; }
        if (q >= 288) { oa0[q-288] = b0[3].x; ob0[q-288] = b0[3].y;
                        oa1[q-288] = b1[3].x; ob1[q-288] = b1[3].y; }
        oa0[q+96]  = b0[4].x; ob0[q+96]  = b0[4].y;
        oa1[q+96]  = b1[4].x; ob1[q+96]  = b1[4].y;
    }
}

// ============ K2 column path (sincos, pair-per-thread, dbuf) ============

__device__ __forceinline__ void col_s1_fwd_pair(const v2f* __restrict__ g, int c0,
                                                v2f* __restrict__ bA, int tid)
{
    constexpr float STEP = -PI2 / 1080.0f;
    const v2f z = vmk(0.f,0.f);
    const float4* gc = (const float4*)(g + c0);
    for (int p = tid; p < 180; p += 256) {
        v2f a0[6], a1[6], b0[6], b1[6];
        a0[0]=a0[5]=a1[0]=a1[5]=z;
        if (p >= 90) { float4 t = gc[(p-90)*960]; a0[1]=vmk(t.x,t.y); a1[1]=vmk(t.z,t.w); }
        else         { a0[1]=a1[1]=z; }
        { float4 t = gc[(p+90)*960];  a0[2]=vmk(t.x,t.y); a1[2]=vmk(t.z,t.w); }
        { float4 t = gc[(p+270)*960]; a0[3]=vmk(t.x,t.y); a1[3]=vmk(t.z,t.w); }
        if (p < 90)  { float4 t = gc[(p+450)*960]; a0[4]=vmk(t.x,t.y); a1[4]=vmk(t.z,t.w); }
        else         { a0[4]=a1[4]=z; }
        dft6<-1>(a0,b0); dft6<-1>(a1,b1);
        float sv, cv; __sincosf(STEP*(float)p, &sv, &cv);
        v2f w[5]; twpow<6>(vmk(cv,sv), w);
        #pragma unroll
        for (int u = 1; u < 6; ++u){ b0[u]=cmul(b0[u],w[u-1]); b1[u]=cmul(b1[u],w[u-1]); }
        #pragma unroll
        for (int u = 0; u < 6; ++u) stp(bA, 6*p + u, b0[u], b1[u]);
    }
}

template<int DIR, int NCUR, int SC>
__device__ __forceinline__ void mid_pair(const v2f* __restrict__ src,
                                         v2f* __restrict__ dst, int tid)
{
    constexpr int NB = 180;
    constexpr float STEP = (float)DIR * PI2 / (float)NCUR;
    for (int ic = tid; ic < NB; ic += 256) {
        const int p = ic / SC;
        v2f a0[6], a1[6], b0[6], b1[6];
        #pragma unroll
        for (int t = 0; t < 6; ++t) ldp(src, ic + NB*t, a0[t], a1[t]);
        dft6<DIR>(a0,b0); dft6<DIR>(a1,b1);
        float sv, cv; __sincosf(STEP*(float)p, &sv, &cv);
        v2f w[5]; twpow<6>(vmk(cv,sv), w);
        #pragma unroll
        for (int u = 1; u < 6; ++u){ b0[u]=cmul(b0[u],w[u-1]); b1[u]=cmul(b1[u],w[u-1]); }
        const int ob = (ic - p*SC) + SC*6*p;
        #pragma unroll
        for (int u = 0; u < 6; ++u) stp(dst, ob + SC*u, b0[u], b1[u]);
    }
}

// ============ K4 B=4 high-radix in-place pieces ============

__device__ __forceinline__ void c4_s1_fwd10(const v2f* __restrict__ Zp, int c0,
                                            float4* __restrict__ sb, int tid)
{
    constexpr float STEP = -PI2 / 1080.0f;
    const v2f z = vmk(0.f,0.f);
    const float4* gc = (const float4*)(Zp + c0);
    const bool act = tid < 216;
    if (act) {
        const int g = tid & 1, p = tid >> 1;
        v2f a0[10], a1[10], b0[10], b1[10];
        a0[0]=a0[1]=a0[8]=a0[9]=z; a1[0]=a1[1]=a1[8]=a1[9]=z;
        if (p >= 54) { float4 t = gc[(p-54)*960+g]; a0[2]=vmk(t.x,t.y); a1[2]=vmk(t.z,t.w); }
        else         { a0[2]=a1[2]=z; }
        { float4 t = gc[(p+54)*960+g];  a0[3]=vmk(t.x,t.y); a1[3]=vmk(t.z,t.w); }
        { float4 t = gc[(p+162)*960+g]; a0[4]=vmk(t.x,t.y); a1[4]=vmk(t.z,t.w); }
        { float4 t = gc[(p+270)*960+g]; a0[5]=vmk(t.x,t.y); a1[5]=vmk(t.z,t.w); }
        { float4 t = gc[(p+378)*960+g]; a0[6]=vmk(t.x,t.y); a1[6]=vmk(t.z,t.w); }
        if (p < 54)  { float4 t = gc[(p+486)*960+g]; a0[7]=vmk(t.x,t.y); a1[7]=vmk(t.z,t.w); }
        else         { a0[7]=a1[7]=z; }
        dft10<-1>(a0,b0); dft10<-1>(a1,b1);
        float sv, cv; __sincosf(STEP*(float)p, &sv, &cv);
        v2f w[9]; twpow<10>(vmk(cv,sv), w);
        #pragma unroll
        for (int u = 1; u < 10; ++u){ b0[u]=cmul(b0[u],w[u-1]); b1[u]=cmul(b1[u],w[u-1]); }
        #pragma unroll
        for (int u = 0; u < 10; ++u) st4g(sb, 10*p+u, g, b0[u], b1[u]);
    }
    __syncthreads();
}

template<int DIR, int NCUR, int SC>
__device__ __forceinline__ void c4_mid12_ip(float4* __restrict__ sb, int tid)
{
    constexpr int NB = (NCUR/12)*SC;   // 90
    constexpr float STEP = (float)DIR * PI2 / (float)NCUR;
    const bool act = tid < 2*NB;
    v2f b0[12], b1[12]; int ob = 0, g = 0;
    if (act) {
        g = tid & 1;
        const int ic = tid >> 1;
        const int p = ic / SC;
        v2f a0[12], a1[12];
        #pragma unroll
        for (int t = 0; t < 12; ++t) ld4g(sb, ic + NB*t, g, a0[t], a1[t]);
        dft12<DIR>(a0,b0); dft12<DIR>(a1,b1);
        float sv, cv; __sincosf(STEP*(float)p, &sv, &cv);
        v2f w[11]; twpow<12>(vmk(cv,sv), w);
        #pragma unroll
        for (int u = 1; u < 12; ++u){ b0[u]=cmul(b0[u],w[u-1]); b1[u]=cmul(b1[u],w[u-1]); }
        ob = (ic - p*SC) + SC*12*p;
    }
    __syncthreads();
    if (act) {
        #pragma unroll
        for (int u = 0; u < 12; ++u) st4g(sb, ob + SC*u, g, b0[u], b1[u]);
    }
    __syncthreads();
}

__device__ __forceinline__ void c4_f9K9_ip(float4* __restrict__ sb,
                                           const float4* __restrict__ KI,
                                           int cg, int tid)
{
    constexpr float STEP = PI2 / 1080.0f;
    const bool act = tid < 240;
    v2f d0[9], d1[9]; int q = 0, g = 0;
    if (act) {
        g = tid & 1; q = tid >> 1;
        const float4* Kc = KI + (cg*2 + g)*1080;
        v2f a0[9], a1[9], s0[9], s1[9];
        #pragma unroll
        for (int u = 0; u < 9; ++u) ld4g(sb, q + 120*u, g, a0[u], a1[u]);
        dft9<-1>(a0,s0); dft9<-1>(a1,s1);
        #pragma unroll
        for (int u = 0; u < 9; ++u) {
            float4 kk = Kc[q + 120*u];
            s0[u] = cmul(s0[u], vmk(kk.x,kk.y));
            s1[u] = cmul(s1[u], vmk(kk.z,kk.w));
        }
        dft9<1>(s0,d0); dft9<1>(s1,d1);
        float sv, cv; __sincosf(STEP*(float)q, &sv, &cv);
        v2f w[8]; twpow<9>(vmk(cv,sv), w);
        #pragma unroll
        for (int u = 1; u < 9; ++u){ d0[u]=cmul(d0[u],w[u-1]); d1[u]=cmul(d1[u],w[u-1]); }
    }
    __syncthreads();
    if (act) {
        #pragma unroll
        for (int u = 0; u < 9; ++u) st4g(sb, 9*q + u, g, d0[u], d1[u]);
    }
    __syncthreads();
}

__device__ __forceinline__ void c4_fin10_crop(const float4* __restrict__ sb,
                                              v2f* __restrict__ Zp,
                                              int c0, int tid)
{
    const bool act = tid < 216;
    if (!act) return;
    const int g = tid & 1, q = tid >> 1;
    float4* gc = (float4*)(Zp + c0);
    v2f a0[10], a1[10], b0[10], b1[10];
    #pragma unroll
    for (int u = 0; u < 10; ++u) ld4g(sb, q + 108*u, g, a0[u], a1[u]);
    dft10<1>(a0,b0); dft10<1>(a1,b1);
    gc[(q+270)*960+g] = pk(b0[0], b1[0]);
    gc[(q+378)*960+g] = pk(b0[1], b1[1]);
    if (q < 54)  gc[(q+486)*960+g] = pk(b0[2], b1[2]);
    if (q >= 54) gc[(q-54)*960+g]  = pk(b0[7], b1[7]);
    gc[(q+54)*960+g]  = pk(b0[8], b1[8]);
    gc[(q+162)*960+g] = pk(b0[9], b1[9]);
}

// ============ kernels ============

// K13: row forward FFTs. Blocks [0,1080): x pairs; [1080,1620): h rows.
__global__ __launch_bounds__(256,5) void k_row_fwd(const float* __restrict__ x,
                                                   const float* __restrict__ h,
                                                   v2f* __restrict__ Z,
                                                   v2f* __restrict__ Hrow)
{
    __shared__ float4 sb[IDX4SZ(1920)];
    const int tid = threadIdx.x;
    if (blockIdx.x < 1080) {
        const int pp = blockIdx.x / 270;
        const int r0 = (blockIdx.x % 270) * 2;
        const float* xa = x + ((2*pp  )*540 + r0)*960;
        const float* xb = x + ((2*pp+1)*540 + r0)*960;
        rp_s1_fwd(xa, xb, sb, tid); __syncthreads();
        rp_mid8_ip<-1>(sb, tid);
        rp_mid6_ip<-1>(sb, tid);
        v2f* Zr0 = Z + (pp*540 + r0)*1920;
        rp_fin5_storeZ(sb, Zr0, Zr0 + 1920, tid);
    } else {
        v2f* bA = (v2f*)sb;
        v2f* bB = bA + IDXSZ(1920);
        const int r = blockIdx.x - 1080;
        row_s1_fwd_h(h + r*960, bA, tid); __syncthreads();
        mid_stage<-1,8,240, 8>(bA, bB, tid); __syncthreads();
        mid_stage<-1,6, 30,64>(bB, bA, tid); __syncthreads();
        row_fin5_store_h(bA, Hrow + r*1920, tid);
    }
}

// K2: column FFTs of Hrow (pair/thread, dbuf) + build pair-interleaved KI.
__global__ __launch_bounds__(256,4) void k_col_fft_h_buildK(const v2f* __restrict__ Hrow,
                                                            const float* __restrict__ mu1,
                                                            float4* __restrict__ KI)
{
    __shared__ v2f bA[IDXPSZ(2160)], bB[IDXPSZ(2160)];
    const int tid = threadIdx.x;
    const int xcd = blockIdx.x & 7, idx = blockIdx.x >> 3;
    const int cpair = xcd*120 + idx, c0 = cpair*2;
    col_s1_fwd_pair(Hrow, c0, bA, tid);  __syncthreads();
    mid_pair<-1,180, 6>(bA, bB, tid);    __syncthreads();
    mid_pair<-1, 30,36>(bB, bA, tid);    __syncthreads();
    const float sc = mu1[4] / ((1.0f + 1e-6f) * 2073600.0f);
    const float cos0 = __cosf(PI2 * (float)(c0  ) * (1.0f/1920.0f));
    const float cos1 = __cosf(PI2 * (float)(c0+1) * (1.0f/1920.0f));
    float4* Kc = KI + cpair*1080;
    for (int p = tid; p < 216; p += 256) {
        v2f a0[5],a1[5],b0[5],b1[5];
        #pragma unroll
        for (int u = 0; u < 5; ++u) ldp(bA, p + 216*u, a0[u], a1[u]);
        dft5<-1>(a0,b0); dft5<-1>(a1,b1);
        #pragma unroll
        for (int u = 0; u < 5; ++u) {
            const int k = p + 216*u;
            const float cosk = __cosf(PI2 * (float)k * (1.0f/1080.0f));
            float m0 = b0[u].x*b0[u].x + b0[u].y*b0[u].y;
            float m1 = b1[u].x*b1[u].x + b1[u].y*b1[u].y;
            float f0 = sc / (1e-6f*m0 + 1e-5f*(4.0f - 2.0f*cosk - 2.0f*cos0) + 4e-5f);
            float f1 = sc / (1e-6f*m1 + 1e-5f*(4.0f - 2.0f*cosk - 2.0f*cos1) + 4e-5f);
            Kc[k] = make_float4(f0*b0[u].x, -f0*b0[u].y, f1*b1[u].x, -f1*b1[u].y);
        }
    }
}

// K4: B=4 columns/block, radix {10,12,[9 K 9],12,10}, IN-PLACE (36.7KB LDS,
// 4 blocks/CU). Grid 1920; XCD swizzle.
__global__ __launch_bounds__(256,4) void k_col_fused(v2f* __restrict__ Z,
                                                     const float4* __restrict__ KI)
{
    __shared__ float4 sb[IDX4SZ(2160)];
    const int tid = threadIdx.x;
    const int xcd = blockIdx.x & 7, idx = blockIdx.x >> 3;   // idx in [0,240)
    const int pp  = idx / 60;
    const int cg  = xcd*60 + (idx - pp*60);                  // col-group [0,480)
    const int c0  = cg*4;
    v2f* Zp = Z + pp*540*1920;
    c4_s1_fwd10(Zp, c0, sb, tid);
    c4_mid12_ip<-1,108,10>(sb, tid);
    c4_f9K9_ip(sb, KI, cg, tid);
    c4_mid12_ip< 1,120, 9>(sb, tid);
    c4_fin10_crop(sb, Zp, c0, tid);
}

// K5: row inverse FFTs, paired rows + crop + split into real outputs.
__global__ __launch_bounds__(256,5) void k_row_inv_out(const v2f* __restrict__ Z,
                                                       float* __restrict__ out)
{
    __shared__ float4 sb[IDX4SZ(1920)];
    const int tid = threadIdx.x;
    const int pp = blockIdx.x / 270;
    const int r0 = (blockIdx.x % 270) * 2;
    const v2f* Zr0 = Z + (pp*540 + r0)*1920;
    rp_s1_inv(Zr0, Zr0 + 1920, sb, tid); __syncthreads();
    rp_mid8_ip<1>(sb, tid);
    rp_mid6_ip<1>(sb, tid);
    float* oa0 = out + ((2*pp  )*540 + r0)*960;
    float* ob0 = out + ((2*pp+1)*540 + r0)*960;
    rp_fin5_crop(sb, oa0, ob0, oa0 + 960, ob0 + 960, tid);
}

extern "C" void kernel_launch(void* const* d_in, const int* in_sizes, int n_in,
                              void* d_out, int out_size, void* d_ws, size_t ws_size,
                              hipStream_t stream)
{
    (void)in_sizes; (void)n_in; (void)out_size; (void)ws_size;
    const float* x   = (const float*)d_in[0];
    const float* h   = (const float*)d_in[1];
    const float* mu1 = (const float*)d_in[2];
    float*       out = (float*)d_out;

    // ws layout: KI (960*1080 f4 = 16.6MB) | Z (4*540*1920 v2f = 33.2MB) |
    // Hrow (540*1920 v2f = 8.3MB).
    float4* KI   = (float4*)d_ws;
    v2f*    Z    = (v2f*)(KI + 960*1080);
    v2f*    Hrow = Z + 4*540*1920;

    k_row_fwd         <<<1620,   256, 0, stream>>>(x, h, Z, Hrow);
    k_col_fft_h_buildK<<<960,    256, 0, stream>>>(Hrow, mu1, KI);
    k_col_fused       <<<1920,   256, 0, stream>>>(Z, KI);
    k_row_inv_out     <<<1080,   256, 0, stream>>>(Z, out);
}